// Round 12
// baseline (328.482 us; speedup 1.0000x reference)
//
#include <hip/hip_runtime.h>
#include <cmath>

#define N_ENT 100000
#define EHALF 1000000
#define N_REL 500
#define NBUK 196          // ceil(100000/512) coarse buckets (key>>9)
#define DPB 512           // entities per bucket
#define SCAP 7680         // src-record region capacity per bucket (4B recs)
#define DCAP 6656         // dst-record / csr region capacity per bucket (8B recs)
#define NSB 512           // split blocks per phase
#define SPAN 1954         // ceil(EHALF/NSB)
#define XFB 391           // ceil(N_ENT/256) Xf-gemm blocks

#ifndef M_PI
#define M_PI 3.14159265358979323846
#endif

typedef _Float16 f16x8 __attribute__((ext_vector_type(8)));
typedef _Float16 f16x4 __attribute__((ext_vector_type(4)));
typedef _Float16 f16x2 __attribute__((ext_vector_type(2)));
typedef float f32x4 __attribute__((ext_vector_type(4)));

union H16 { unsigned short u; _Float16 h; };
union HU32 { unsigned u; f16x2 h; };

// ---------------- L1: DFT tables + cursor/bnAcc zeroing ----------------
__global__ void k_tabs(float* __restrict__ Ftab, float* __restrict__ Gtab,
                       _Float16* __restrict__ FtabT,
                       int* __restrict__ gcur, float* __restrict__ bnAcc) {
  if (blockIdx.x == 0) {
    for (int j = threadIdx.x; j < 4 * NBUK; j += 256) gcur[j] = 0;
    bnAcc[threadIdx.x] = 0.f;
  }
  int i = blockIdx.x * 256 + threadIdx.x;
  if (i >= 128 * 128) return;
  int n = i >> 7, s = i & 127;
  float fv, gv;
  if (s == 0) { fv = 1.f; gv = 1.f / 384.f; }
  else if (s == 1) { float sg = (n & 1) ? -1.f : 1.f; fv = sg; gv = sg / 384.f; }
  else {
    int f = s >> 1;
    double ang = 2.0 * M_PI * (double)((f * n) & 127) / 128.0;
    if (!(s & 1)) { double c = cos(ang); fv = (float)c; gv = (float)(c * (2.0 / 384.0)); }
    else { double sv = sin(ang); fv = (float)(-sv); gv = (float)(-sv * (2.0 / 384.0)); }
  }
  Ftab[n * 128 + s] = fv;
  Gtab[s * 128 + n] = gv;
  FtabT[s * 128 + n] = (_Float16)fv;
}

// ---------------- device bodies ----------------
// fp32 GEMM body, N fixed = 128. smem >= 49152 bytes.
__device__ void gemm128_body(char* smem, const float* __restrict__ A, int lda,
                             const float* __restrict__ B,
                             float* __restrict__ C, int ldc,
                             int M, int K, int m0) {
  float (*As)[64] = (float(*)[64])smem;
  float (*Bs)[128] = (float(*)[128])(smem + 64 * 64 * 4);
  const int t = threadIdx.x;
  const int cg = t & 31;
  const int eg = t >> 5;
  float acc[8][4];
#pragma unroll
  for (int i = 0; i < 8; ++i)
#pragma unroll
    for (int j = 0; j < 4; ++j) acc[i][j] = 0.f;

  for (int k0 = 0; k0 < K; k0 += 64) {
#pragma unroll
    for (int p = 0; p < 4; ++p) {
      int idx = t + p * 256;
      int r = idx >> 4, c4 = idx & 15;
      int gr = m0 + r;
      float4 v = make_float4(0.f, 0.f, 0.f, 0.f);
      if (gr < M) v = *(const float4*)(A + (size_t)gr * lda + k0 + c4 * 4);
      *(float4*)&As[r][c4 * 4] = v;
    }
#pragma unroll
    for (int p = 0; p < 8; ++p) {
      int idx = t + p * 256;
      int r = idx >> 5, c4 = idx & 31;
      float4 v = *(const float4*)(B + (size_t)(k0 + r) * 128 + c4 * 4);
      *(float4*)&Bs[r][c4 * 4] = v;
    }
    __syncthreads();
#pragma unroll
    for (int k = 0; k < 64; ++k) {
      float4 bv = *(float4*)&Bs[k][cg * 4];
#pragma unroll
      for (int i = 0; i < 8; ++i) {
        float av = As[eg * 8 + i][k];
        acc[i][0] += av * bv.x; acc[i][1] += av * bv.y;
        acc[i][2] += av * bv.z; acc[i][3] += av * bv.w;
      }
    }
    __syncthreads();
  }
#pragma unroll
  for (int i = 0; i < 8; ++i) {
    int gr = m0 + eg * 8 + i;
    if (gr < M) {
      float4 v = make_float4(acc[i][0], acc[i][1], acc[i][2], acc[i][3]);
      *(float4*)(C + (size_t)gr * ldc + cg * 4) = v;
    }
  }
}

__device__ inline f16x8 loadAfrag(const _Float16* A, size_t off) {
  return *(const f16x8*)(A + off);
}
__device__ inline f16x8 loadAfrag(const float* A, size_t off) {
  float4 u = *(const float4*)(A + off);
  float4 v = *(const float4*)(A + off + 4);
  return (f16x8){(_Float16)u.x, (_Float16)u.y, (_Float16)u.z, (_Float16)u.w,
                 (_Float16)v.x, (_Float16)v.y, (_Float16)v.z, (_Float16)v.w};
}

// f16 MFMA GEMM body, N=128. MODE 1: f16 C plain. MODE 2: +bias +BN stats.
// lds >= 128*KS*2 + 4096 bytes.
template<int K, int KS, int MODE, typename AT>
__device__ void mgemm_body(char* lds, int bid,
                           const AT* __restrict__ A, int lda,
                           const _Float16* __restrict__ BT,
                           _Float16* __restrict__ C, int ldc, int M,
                           const float* __restrict__ bias, float* __restrict__ bnAcc) {
  const int t = threadIdx.x;
  const int l = t & 63, w = t >> 6;
  const int col0 = l & 15, rg = l >> 4;
  const int rowbase = bid * 256 + w * 64;
  const int sw = (col0 & 7) << 4;

  f32x4 acc[4][8];
  f32x4 zz = {0.f, 0.f, 0.f, 0.f};
#pragma unroll
  for (int a = 0; a < 4; ++a)
#pragma unroll
    for (int n = 0; n < 8; ++n) acc[a][n] = zz;

  for (int ks0 = 0; ks0 < K; ks0 += KS) {
    __syncthreads();
    const int CH = KS / 8;
    for (int u = t; u < 128 * CH; u += 256) {
      int col = u / CH, kc = u % CH;
      f16x8 vch = *(const f16x8*)(BT + (size_t)col * K + ks0 + kc * 8);
      *(f16x8*)(lds + col * (KS * 2) + ((kc * 16) ^ ((col & 7) << 4))) = vch;
    }
    __syncthreads();
#pragma unroll
    for (int ks = 0; ks < KS / 32; ++ks) {
      int kb = ks0 + ks * 32 + rg * 8;
      f16x8 af[4];
#pragma unroll
      for (int a = 0; a < 4; ++a) {
        int rb = rowbase + a * 16;
        if (rb < M) af[a] = loadAfrag(A, (size_t)(rb + col0) * lda + kb);
        else af[a] = (f16x8){0, 0, 0, 0, 0, 0, 0, 0};
      }
      int kc = ks * 4 + rg;
#pragma unroll
      for (int n = 0; n < 8; ++n) {
        f16x8 bf = *(const f16x8*)(lds + (n * 16 + col0) * (KS * 2) + ((kc * 16) ^ sw));
#pragma unroll
        for (int a = 0; a < 4; ++a)
          acc[a][n] = __builtin_amdgcn_mfma_f32_16x16x32_f16(af[a], bf, acc[a][n], 0, 0, 0);
      }
    }
  }

  if (MODE == 1) {
#pragma unroll
    for (int a = 0; a < 4; ++a) {
      int rb = rowbase + a * 16;
      if (rb >= M) continue;
#pragma unroll
      for (int r = 0; r < 4; ++r) {
        int row = rb + rg * 4 + r;
#pragma unroll
        for (int n = 0; n < 8; ++n) {
          int col = n * 16 + col0;
          C[(size_t)row * ldc + col] = (_Float16)acc[a][n][r];
        }
      }
    }
  } else {
    float sacc[8], qacc[8];
#pragma unroll
    for (int n = 0; n < 8; ++n) { sacc[n] = 0.f; qacc[n] = 0.f; }
#pragma unroll
    for (int a = 0; a < 4; ++a) {
      int rb = rowbase + a * 16;
      if (rb >= M) continue;
#pragma unroll
      for (int n = 0; n < 8; ++n) {
        int col = n * 16 + col0;
        float bi = bias[col];
#pragma unroll
        for (int r = 0; r < 4; ++r) {
          float val = acc[a][n][r] + bi;
          C[(size_t)(rb + rg * 4 + r) * ldc + col] = (_Float16)val;
          sacc[n] += val; qacc[n] += val * val;
        }
      }
    }
    __syncthreads();
    float* Sb = (float*)lds;
    float* Qb = Sb + 512;
#pragma unroll
    for (int n = 0; n < 8; ++n) {
      float s = sacc[n], q = qacc[n];
      s += __shfl_xor(s, 16); s += __shfl_xor(s, 32);
      q += __shfl_xor(q, 16); q += __shfl_xor(q, 32);
      if (rg == 0) { Sb[w * 128 + n * 16 + col0] = s; Qb[w * 128 + n * 16 + col0] = q; }
    }
    __syncthreads();
    if (t < 128) {
      float s = Sb[t] + Sb[128 + t] + Sb[256 + t] + Sb[384 + t];
      float q = Qb[t] + Qb[128 + t] + Qb[256 + t] + Qb[384 + t];
      atomicAdd(&bnAcc[t], s);
      atomicAdd(&bnAcc[128 + t], q);
    }
  }
}

// merged split body (4 grid-parallel phases). smem >= 3136 bytes.
__device__ void split_body(char* smem, int bid,
                           const int* __restrict__ ei, const int* __restrict__ et,
                           int* __restrict__ gcur,
                           unsigned* __restrict__ recSI, unsigned* __restrict__ recSO,
                           uint2* __restrict__ recDI, uint2* __restrict__ recDO) {
  int* bcnt = (int*)smem;
  int* cnt2 = bcnt + NBUK;
  int* base = cnt2 + NBUK;
  int* nn   = base + NBUK;
  const int t = threadIdx.x;
  const int ph = bid >> 9;
  const int blk = bid & 511;
  const int st = blk * SPAN;
  const int en = min(st + SPAN, EHALF);

  if (t < NBUK) { bcnt[t] = 0; cnt2[t] = 0; }
  __syncthreads();

  if (ph < 2) {
    const int* key = ei + (ph ? EHALF : 0);
    int* gc = gcur + ph * NBUK;
    unsigned* rec = ph ? recSO : recSI;
    unsigned rr[8]; int bb[8];
#pragma unroll
    for (int j = 0; j < 8; ++j) {
      int e = st + j * 256 + t;
      bb[j] = -1;
      if (e < en) {
        int s = key[e];
        rr[j] = (unsigned)(s & 511) | 0x80000000u;
        bb[j] = s >> 9;
        atomicAdd(&bcnt[bb[j]], 1);
      }
    }
    __syncthreads();
    if (t < NBUK) {
      int n = bcnt[t]; nn[t] = n;
      base[t] = n ? (t * SCAP + atomicAdd(&gc[t], (n + 7) & ~7)) : 0;
    }
    __syncthreads();
#pragma unroll
    for (int j = 0; j < 8; ++j) {
      if (bb[j] >= 0) {
        int p = atomicAdd(&cnt2[bb[j]], 1);
        rec[(size_t)base[bb[j]] + p] = rr[j];
      }
    }
    __syncthreads();
    if (t < NBUK) {
      int n = nn[t];
      if (n & 7) {
        int pe = (n + 7) & ~7;
        for (int k = n; k < pe; ++k) rec[(size_t)base[t] + k] = 0u;
      }
    }
  } else {
    const int dir = ph - 2;
    const int* srcA = ei + (dir ? EHALF : 0);
    const int* dstA = ei + (dir ? 3 * EHALF : 2 * EHALF);
    const int* typA = et + (dir ? EHALF : 0);
    int* gc = gcur + (2 + dir) * NBUK;
    uint2* rec = dir ? recDO : recDI;
    unsigned w0[8], w1[8]; int bb[8];
#pragma unroll
    for (int j = 0; j < 8; ++j) {
      int e = st + j * 256 + t;
      bb[j] = -1;
      if (e < en) {
        int s = srcA[e], d = dstA[e], ty = typA[e];
        w0[j] = (unsigned)s | ((unsigned)ty << 17);
        w1[j] = (unsigned)(d & 511) | 0x80000000u;
        bb[j] = d >> 9;
        atomicAdd(&bcnt[bb[j]], 1);
      }
    }
    __syncthreads();
    if (t < NBUK) {
      int n = bcnt[t]; nn[t] = n;
      base[t] = n ? (t * DCAP + atomicAdd(&gc[t], (n + 3) & ~3)) : 0;
    }
    __syncthreads();
#pragma unroll
    for (int j = 0; j < 8; ++j) {
      if (bb[j] >= 0) {
        int p = atomicAdd(&cnt2[bb[j]], 1);
        rec[(size_t)base[bb[j]] + p] = make_uint2(w0[j], w1[j]);
      }
    }
    __syncthreads();
    if (t < NBUK) {
      int n = nn[t];
      if (n & 3) {
        int pe = (n + 3) & ~3;
        for (int k = n; k < pe; ++k) rec[(size_t)base[t] + k] = make_uint2(0u, 0u);
      }
    }
  }
}

// Rf spectra + per-lane pack, 2 rels per 256-thr block. smem >= 1024 bytes.
__device__ void dftrel_body(char* smem, int blk,
                            const float* __restrict__ rel, const float* __restrict__ looprel,
                            const float* __restrict__ Ftab, float* __restrict__ Rf,
                            _Float16* __restrict__ RfL) {
  float* sv = (float*)smem;  // 256 floats
  int t = threadIdx.x;
  int r = blk * 2 + (t >> 7);
  int s = t & 127;
  if (r < 501) {
    const float* row = (r < N_REL) ? rel + (size_t)r * 128 : looprel;
    float acc = 0.f;
    for (int n = 0; n < 128; ++n) acc += row[n] * Ftab[n * 128 + s];
    Rf[(size_t)r * 128 + s] = acc;
    sv[t] = acc;
  }
  __syncthreads();
  if (r < 501 && s < 64) {
    int bse = t & 128;
    f16x4 o;
    if (s == 0) {
      o = (f16x4){(_Float16)sv[bse], (_Float16)0.f, (_Float16)0.f, (_Float16)sv[bse + 1]};
    } else {
      float rx = sv[bse + 2 * s], ry = sv[bse + 2 * s + 1];
      o = (f16x4){(_Float16)rx, (_Float16)ry, (_Float16)ry, (_Float16)(-rx)};
    }
    ((f16x4*)RfL)[(size_t)r * 64 + s] = o;
  }
}

// degree hist -> dinv, 256 threads. smem >= 2048 bytes.
__device__ void dhist_body(char* smem, int bid,
                           const unsigned* __restrict__ recI, const int* __restrict__ gI,
                           float* __restrict__ dinvIn,
                           const unsigned* __restrict__ recO, const int* __restrict__ gO,
                           float* __restrict__ dinvOut) {
  int b = bid % NBUK;
  int dir = bid / NBUK;
  const unsigned* rec = dir ? recO : recI;
  const int gs = b * SCAP;
  const int ge = gs + (dir ? gO : gI)[b];
  float* dinv = dir ? dinvOut : dinvIn;
  int* h = (int*)smem;  // 512 ints
  int t = threadIdx.x;
  h[t] = 0; h[t + 256] = 0;
  __syncthreads();
  for (int i = gs + t; i < ge; i += 256) {
    unsigned r = rec[i];
    if (r >> 31) atomicAdd(&h[r & 511], 1);
  }
  __syncthreads();
#pragma unroll
  for (int j = 0; j < 2; ++j) {
    int bin = t + j * 256;
    int ent = b * 512 + bin;
    if (ent < N_ENT) {
      int d = h[bin];
      dinv[ent] = (d > 0) ? rsqrtf((float)d) : 0.f;
    }
  }
}

// fine sort (512 thr). smem >= 8448 bytes.
__device__ void fsort_body(char* smem, int bid,
                           const uint2* __restrict__ recDI, const int* __restrict__ gDI,
                           uint2* __restrict__ csrIn, int2* __restrict__ beI,
                           const uint2* __restrict__ recDO, const int* __restrict__ gDO,
                           uint2* __restrict__ csrOut, int2* __restrict__ beO,
                           const float* __restrict__ dinvIn, const float* __restrict__ dinvOut) {
  int b = bid % NBUK;
  int dir = bid / NBUK;
  const uint2* rec = dir ? recDO : recDI;
  const int gs = b * DCAP;
  const int ge = gs + (dir ? gDO : gDI)[b];
  const float* dinv = dir ? dinvOut : dinvIn;
  uint2* csr = dir ? csrOut : csrIn;
  int2* be = dir ? beO : beI;
  int* h  = (int*)smem;
  int* sc = h + 512;
  int* c2 = sc + 512;
  float* dl = (float*)(c2 + 512);
  int* totv = (int*)(dl + 512);
  int t = threadIdx.x;
  int ent = b * 512 + t;
  h[t] = 0; c2[t] = 0;
  dl[t] = (ent < N_ENT) ? dinv[ent] : 0.f;
  __syncthreads();
  for (int i = gs + t; i < ge; i += 512) {
    uint2 r = rec[i];
    if (r.y >> 31) atomicAdd(&h[r.y & 511], 1);
  }
  __syncthreads();
  sc[t] = h[t];
  __syncthreads();
  for (int o = 1; o < 512; o <<= 1) {
    int a = (t >= o) ? sc[t - o] : 0;
    __syncthreads();
    sc[t] += a;
    __syncthreads();
  }
  int excl = sc[t] - h[t];
  if (t == 511) *totv = sc[511];
  if (ent < N_ENT) be[ent] = make_int2(gs + excl, gs + excl + h[t]);
  __syncthreads();
  sc[t] = excl;
  __syncthreads();
  if (t < 8) csr[(size_t)gs + *totv + t] = make_uint2(0u, 0u);
  for (int i = gs + t; i < ge; i += 512) {
    uint2 r = rec[i];
    if (r.y >> 31) {
      int d = r.y & 511;
      unsigned src = r.x & 0x1FFFFu;
      float nm = dinv[src] * dl[d];
      H16 cv; cv.h = (_Float16)nm;
      int p = atomicAdd(&c2[d], 1);
      csr[(size_t)gs + sc[d] + p] =
          make_uint2((src * 3u) << 8,                       // src*768 bytes
                     (r.x >> 17) | ((unsigned)cv.u << 16)); // typ | norm<<16
    }
  }
}

// W transpose + loop-rel rotation, 512 threads
__device__ void wt_body(int wb, const float* __restrict__ W, const float* __restrict__ Rfl,
                        _Float16* __restrict__ WT) {
  int i = wb * 512 + threadIdx.x;
  if (i >= 384 * 128) return;
  int k = i >> 7, c = i & 127;
  float val;
  if (k < 256) {
    val = W[i];
  } else {
    int kk = k - 256;
    if (kk == 0)      val = Rfl[0] * W[i];
    else if (kk == 1) val = Rfl[1] * W[i];
    else {
      int f = kk >> 1;
      float rr = Rfl[2 * f], ri = Rfl[2 * f + 1];
      float a = W[(256 + 2 * f) * 128 + c];
      float b = W[(256 + 2 * f + 1) * 128 + c];
      val = (kk & 1) ? (ri * a - rr * b) : (rr * a + ri * b);
    }
  }
  WT[(size_t)c * 384 + k] = (_Float16)val;
}

// BN normalize body. smem >= 1024 bytes.
__device__ void norm_body(char* smem, int bid, const _Float16* __restrict__ tmp,
                          float* __restrict__ out, const float* __restrict__ bnAcc,
                          const float* __restrict__ bnw, const float* __restrict__ bnb) {
  float* ss = (float*)smem;
  int t = threadIdx.x;
  if (t < 128) {
    float mu = bnAcc[t] * (1.f / (float)N_ENT);
    float var = bnAcc[128 + t] * (1.f / (float)N_ENT) - mu * mu;
    float sc = bnw[t] * rsqrtf(var + 1e-5f);
    ss[t] = sc; ss[128 + t] = bnb[t] - mu * sc;
  }
  __syncthreads();
  int i = bid * 256 + t;
  f16x8 v = ((const f16x8*)tmp)[i];
  int cb = (i & 15) * 8;
  float4 o0, o1;
  o0.x = (float)v[0] * ss[cb]     + ss[128 + cb];
  o0.y = (float)v[1] * ss[cb + 1] + ss[129 + cb];
  o0.z = (float)v[2] * ss[cb + 2] + ss[130 + cb];
  o0.w = (float)v[3] * ss[cb + 3] + ss[131 + cb];
  o1.x = (float)v[4] * ss[cb + 4] + ss[132 + cb];
  o1.y = (float)v[5] * ss[cb + 5] + ss[133 + cb];
  o1.z = (float)v[6] * ss[cb + 6] + ss[134 + cb];
  o1.w = (float)v[7] * ss[cb + 7] + ss[135 + cb];
  ((float4*)out)[2 * i] = o0;
  ((float4*)out)[2 * i + 1] = o1;
}

// ---------------- fused kernels ----------------
// L2: Xf-GEMM || split (4 phases) || rel-DFT
__global__ __launch_bounds__(256) void k_front(
    const float* __restrict__ x, const _Float16* __restrict__ FtabT, _Float16* __restrict__ Abuf,
    const int* __restrict__ ei, const int* __restrict__ et, int* __restrict__ gcur,
    unsigned* __restrict__ recSI, unsigned* __restrict__ recSO,
    uint2* __restrict__ recDI, uint2* __restrict__ recDO,
    const float* __restrict__ rel, const float* __restrict__ looprel,
    const float* __restrict__ Ftab, float* __restrict__ Rf, _Float16* __restrict__ RfL) {
  __shared__ __align__(16) char smem[37120];
  int b = blockIdx.x;
  if (b < XFB) {
    mgemm_body<128, 128, 1, float>(smem, b, x, 128, FtabT, Abuf + 256, 384, N_ENT,
                                   nullptr, nullptr);
  } else if (b < XFB + 4 * NSB) {
    split_body(smem, b - XFB, ei, et, gcur, recSI, recSO, recDI, recDO);
  } else {
    dftrel_body(smem, b - XFB - 4 * NSB, rel, looprel, Ftab, Rf, RfL);
  }
}

// L3: Wstack prep GEMMs || degree hist
__global__ __launch_bounds__(256) void k_mid1(
    const float* __restrict__ Gtab, const float* __restrict__ w0,
    const float* __restrict__ w1, const float* __restrict__ w2, float* __restrict__ Wstack,
    const unsigned* __restrict__ recSI, const int* __restrict__ gSI, float* __restrict__ dinvIn,
    const unsigned* __restrict__ recSO, const int* __restrict__ gSO, float* __restrict__ dinvOut) {
  __shared__ __align__(16) char smem[49280];
  int b = blockIdx.x;
  if (b < 6) {
    int which = b >> 1;
    const float* B = (which == 0) ? w0 : ((which == 1) ? w1 : w2);
    gemm128_body(smem, Gtab, 128, B, Wstack + which * 128 * 128, 128, 128, 128, (b & 1) * 64);
  } else {
    dhist_body(smem, b - 6, recSI, gSI, dinvIn, recSO, gSO, dinvOut);
  }
}

// L4: fine sort || WT transpose
__global__ __launch_bounds__(512) void k_mid2(
    const uint2* __restrict__ recDI, const int* __restrict__ gDI,
    uint2* __restrict__ csrIn, int2* __restrict__ beI,
    const uint2* __restrict__ recDO, const int* __restrict__ gDO,
    uint2* __restrict__ csrOut, int2* __restrict__ beO,
    const float* __restrict__ dinvIn, const float* __restrict__ dinvOut,
    const float* __restrict__ Wstack, const float* __restrict__ Rfl, _Float16* __restrict__ WT) {
  __shared__ __align__(16) char smem[8448];
  int b = blockIdx.x;
  if (b < 2 * NBUK) {
    fsort_body(smem, b, recDI, gDI, csrIn, beI, recDO, gDO, csrOut, beO, dinvIn, dinvOut);
  } else {
    wt_body(b - 2 * NBUK, Wstack, Rfl, WT);
  }
}

// L6 wrapper: fused output GEMM (MODE 2)
__global__ __launch_bounds__(256) void k_mgemm384(
    const _Float16* __restrict__ A, const _Float16* __restrict__ BT,
    _Float16* __restrict__ C, int M,
    const float* __restrict__ bias, float* __restrict__ bnAcc) {
  __shared__ __align__(16) char lds[53504];
  mgemm_body<384, 192, 2, _Float16>(lds, blockIdx.x, A, 384, BT, C, 128, M, bias, bnAcc);
}

// L7: rel_out GEMM || BN normalize
__global__ __launch_bounds__(256) void k_back(
    const float* __restrict__ rel, const float* __restrict__ w_rel, float* __restrict__ out,
    const _Float16* __restrict__ tmp, const float* __restrict__ bnAcc,
    const float* __restrict__ bnw, const float* __restrict__ bnb) {
  __shared__ __align__(16) char smem[49280];
  int b = blockIdx.x;
  if (b < 8) {
    gemm128_body(smem, rel, 128, w_rel, out + (size_t)N_ENT * 128, 128, N_REL, 128, b * 64);
  } else {
    norm_body(smem, b - 8, tmp, out, bnAcc, bnw, bnb);
  }
}

// ---------------- L5: frequency-domain edge aggregation ----------------
__device__ inline float dot2f(f16x2 a, f16x2 b, float c) {
#if __has_builtin(__builtin_amdgcn_fdot2)
  return __builtin_amdgcn_fdot2(a, b, c, false);
#else
  return fmaf((float)a[0], (float)b[0], fmaf((float)a[1], (float)b[1], c));
#endif
}

__device__ inline void b4load(const uint2* __restrict__ csr, int base,
                              const char* __restrict__ Xb, const char* __restrict__ Rb,
                              unsigned lxc, unsigned lr,
                              uint2 q[4], f16x2 xv[4], f16x4 rv[4]) {
#pragma unroll
  for (int j = 0; j < 4; ++j) q[j] = csr[base + j];
#pragma unroll
  for (int j = 0; j < 4; ++j) {
    xv[j] = *(const f16x2*)(Xb + q[j].x + lxc);
    rv[j] = *(const f16x4*)(Rb + ((q[j].y & 0x1FFu) << 9) + lr);
  }
}
__device__ inline void b4math(const uint2 q[4], int base, int end,
                              const f16x2 xv[4], const f16x4 rv[4],
                              float& ax, float& ay) {
#pragma unroll
  for (int j = 0; j < 4; ++j) {
    unsigned nb = (base + j < end) ? (q[j].y >> 16) : 0u;
    HU32 nm; nm.u = nb | (nb << 16);
    f16x2 xs = xv[j] * nm.h;
    ax = dot2f(xs, (f16x2){rv[j][0], rv[j][1]}, ax);
    ay = dot2f(xs, (f16x2){rv[j][2], rv[j][3]}, ay);
  }
}

__global__ __launch_bounds__(256) void k_agg(
    _Float16* __restrict__ Abuf, const _Float16* __restrict__ RfL,
    const uint2* __restrict__ csrIn, const int2* __restrict__ beI,
    const uint2* __restrict__ csrOut, const int2* __restrict__ beO) {
  const int w = threadIdx.x >> 6, l = threadIdx.x & 63;
  const int v = blockIdx.x * 4 + w;
  const char* Xb = (const char*)Abuf;
  const char* Rb = (const char*)RfL;
  const unsigned lxc = 512u + (unsigned)l * 4u;
  const unsigned lr = (unsigned)l * 8u;
  int2 bi = beI[v], bo = beO[v];
  int i  = __builtin_amdgcn_readfirstlane(bi.x);
  int ie = __builtin_amdgcn_readfirstlane(bi.y);
  int o  = __builtin_amdgcn_readfirstlane(bo.x);
  int oe = __builtin_amdgcn_readfirstlane(bo.y);
  int nbi = (ie - i + 3) >> 2;
  int nbo = (oe - o + 3) >> 2;
  float aix = 0.f, aiy = 0.f, aox = 0.f, aoy = 0.f;

  while (nbi > 0 && nbo > 0) {
    uint2 qa[4], qb[4]; f16x2 xa[4], xb[4]; f16x4 ra[4], rb[4];
    b4load(csrIn, i, Xb, Rb, lxc, lr, qa, xa, ra);
    b4load(csrOut, o, Xb, Rb, lxc, lr, qb, xb, rb);
    b4math(qa, i, ie, xa, ra, aix, aiy);
    b4math(qb, o, oe, xb, rb, aox, aoy);
    i += 4; o += 4; --nbi; --nbo;
  }
  while (nbi > 0) {
    uint2 qa[4]; f16x2 xa[4]; f16x4 ra[4];
    b4load(csrIn, i, Xb, Rb, lxc, lr, qa, xa, ra);
    b4math(qa, i, ie, xa, ra, aix, aiy);
    i += 4; --nbi;
  }
  while (nbo > 0) {
    uint2 qb[4]; f16x2 xb[4]; f16x4 rb[4];
    b4load(csrOut, o, Xb, Rb, lxc, lr, qb, xb, rb);
    b4math(qb, o, oe, xb, rb, aox, aoy);
    o += 4; --nbo;
  }

  *(f16x2*)((char*)Abuf + (size_t)v * 768 + 4u * l) = (f16x2){(_Float16)aix, (_Float16)aiy};
  *(f16x2*)((char*)Abuf + (size_t)v * 768 + 256 + 4u * l) = (f16x2){(_Float16)aox, (_Float16)aoy};
}

extern "C" void kernel_launch(void* const* d_in, const int* in_sizes, int n_in,
                              void* d_out, int out_size, void* d_ws, size_t ws_size,
                              hipStream_t stream) {
  const float* x       = (const float*)d_in[0];
  const float* rel     = (const float*)d_in[1];
  const float* w_in    = (const float*)d_in[2];
  const float* w_out   = (const float*)d_in[3];
  const float* w_loop  = (const float*)d_in[4];
  const float* w_rel   = (const float*)d_in[5];
  const float* looprel = (const float*)d_in[6];
  const float* bias    = (const float*)d_in[7];
  const float* bnw     = (const float*)d_in[8];
  const float* bnb     = (const float*)d_in[9];
  const int*   ei      = (const int*)d_in[10];
  const int*   et      = (const int*)d_in[11];
  float* out = (float*)d_out;

  char* p = (char*)d_ws;
  auto alloc = [&](size_t bytes) -> void* {
    void* r = (void*)p;
    p += (bytes + 255) & ~(size_t)255;
    return r;
  };
  _Float16* Abuf  = (_Float16*)alloc((size_t)N_ENT * 384 * 2);
  _Float16* tmpC  = (_Float16*)alloc((size_t)N_ENT * 128 * 2);
  _Float16* WT    = (_Float16*)alloc(128 * 384 * 2);
  _Float16* FtabT = (_Float16*)alloc(128 * 128 * 2);
  _Float16* RfL   = (_Float16*)alloc(501 * 64 * 4 * 2);
  float* Wstack   = (float*)alloc(384 * 128 * 4);
  float* Ftab     = (float*)alloc(128 * 128 * 4);
  float* Gtab     = (float*)alloc(128 * 128 * 4);
  float* Rf       = (float*)alloc(501 * 128 * 4);
  float* dinvIn   = (float*)alloc(N_ENT * 4);
  float* dinvOut  = (float*)alloc(N_ENT * 4);
  int*   gcur     = (int*)alloc(4 * NBUK * 4);   // gSI|gSO|gDI|gDO (relative)
  int2*  beI      = (int2*)alloc((size_t)N_ENT * 8);
  int2*  beO      = (int2*)alloc((size_t)N_ENT * 8);
  unsigned* recSI = (unsigned*)alloc((size_t)NBUK * SCAP * 4);
  unsigned* recSO = (unsigned*)alloc((size_t)NBUK * SCAP * 4);
  uint2* recDI    = (uint2*)alloc((size_t)NBUK * DCAP * 8);
  uint2* recDO    = (uint2*)alloc((size_t)NBUK * DCAP * 8);
  uint2* csrIn    = (uint2*)alloc((size_t)NBUK * DCAP * 8);
  uint2* csrOut   = (uint2*)alloc((size_t)NBUK * DCAP * 8);
  float* bnAcc    = (float*)alloc(256 * 4);

  int* gSI = gcur;
  int* gSO = gcur + NBUK;
  int* gDI = gcur + 2 * NBUK;
  int* gDO = gcur + 3 * NBUK;

  // L1: tables + cursor/bnAcc zeroing
  k_tabs<<<64, 256, 0, stream>>>(Ftab, Gtab, FtabT, gcur, bnAcc);

  // L2: Xf-GEMM || split (4 phases) || rel-DFT
  k_front<<<XFB + 4 * NSB + 251, 256, 0, stream>>>(
      x, FtabT, Abuf, ei, et, gcur, recSI, recSO, recDI, recDO,
      rel, looprel, Ftab, Rf, RfL);

  // L3: Wstack prep || degree hist -> dinv
  k_mid1<<<6 + 2 * NBUK, 256, 0, stream>>>(
      Gtab, w_in, w_out, w_loop, Wstack, recSI, gSI, dinvIn, recSO, gSO, dinvOut);

  // L4: fine sort -> CSR || WT transpose (+loop-rel rotation)
  k_mid2<<<2 * NBUK + 96, 512, 0, stream>>>(
      recDI, gDI, csrIn, beI, recDO, gDO, csrOut, beO, dinvIn, dinvOut,
      Wstack, Rf + 500 * 128, WT);

  // L5: frequency-domain aggregation
  k_agg<<<N_ENT / 4, 256, 0, stream>>>(Abuf, RfL, csrIn, beI, csrOut, beO);

  // L6: fused output GEMM + bias -> f16 tmp + BN stats
  k_mgemm384<<<XFB, 256, 0, stream>>>(Abuf, WT, tmpC, N_ENT, bias, bnAcc);

  // L7: rel_out GEMM || BN normalize -> fp32 out
  k_back<<<8 + (N_ENT * 128 / 8) / 256, 256, 0, stream>>>(
      rel, w_rel, out, tmpC, bnAcc, bnw, bnb);
}

// Round 13
// 299.195 us; speedup vs baseline: 1.0979x; 1.0979x over previous
//
#include <hip/hip_runtime.h>
#include <cmath>

#define N_ENT 100000
#define EHALF 1000000
#define N_REL 500
#define NBUK 196          // ceil(100000/512) coarse buckets (key>>9)
#define DPB 512           // entities per bucket
#define SCAP 7680         // src-record region capacity per bucket (4B recs)
#define DCAP 6656         // dst-record / csr region capacity per bucket (8B recs)
#define NSB 512           // split blocks per phase
#define SPAN 1954         // ceil(EHALF/NSB)
#define XFB 391           // ceil(N_ENT/256) MFMA-gemm blocks

#ifndef M_PI
#define M_PI 3.14159265358979323846
#endif

typedef _Float16 f16x8 __attribute__((ext_vector_type(8)));
typedef _Float16 f16x4 __attribute__((ext_vector_type(4)));
typedef _Float16 f16x2 __attribute__((ext_vector_type(2)));
typedef float f32x4 __attribute__((ext_vector_type(4)));

union H16 { unsigned short u; _Float16 h; };
union HU32 { unsigned u; f16x2 h; };

// ---------------- L1: DFT tables + cursor/bnAcc zeroing ----------------
__global__ void k_tabs(float* __restrict__ Ftab, float* __restrict__ Gtab,
                       _Float16* __restrict__ FtabT,
                       int* __restrict__ gcur, float* __restrict__ bnAcc) {
  if (blockIdx.x == 0) {
    for (int j = threadIdx.x; j < 4 * NBUK; j += 256) gcur[j] = 0;
    bnAcc[threadIdx.x] = 0.f;
  }
  int i = blockIdx.x * 256 + threadIdx.x;
  if (i >= 128 * 128) return;
  int n = i >> 7, s = i & 127;
  float fv, gv;
  if (s == 0) { fv = 1.f; gv = 1.f / 384.f; }
  else if (s == 1) { float sg = (n & 1) ? -1.f : 1.f; fv = sg; gv = sg / 384.f; }
  else {
    int f = s >> 1;
    double ang = 2.0 * M_PI * (double)((f * n) & 127) / 128.0;
    if (!(s & 1)) { double c = cos(ang); fv = (float)c; gv = (float)(c * (2.0 / 384.0)); }
    else { double sv = sin(ang); fv = (float)(-sv); gv = (float)(-sv * (2.0 / 384.0)); }
  }
  Ftab[n * 128 + s] = fv;
  Gtab[s * 128 + n] = gv;
  FtabT[s * 128 + n] = (_Float16)fv;
}

// ---------------- device bodies ----------------
// fp32 GEMM body, N fixed = 128 (prep GEMMs). smem >= 49152 bytes.
__device__ void gemm128_body(char* smem, const float* __restrict__ A, int lda,
                             const float* __restrict__ B,
                             float* __restrict__ C, int ldc,
                             int M, int K, int m0) {
  float (*As)[64] = (float(*)[64])smem;
  float (*Bs)[128] = (float(*)[128])(smem + 64 * 64 * 4);
  const int t = threadIdx.x;
  const int cg = t & 31;
  const int eg = t >> 5;
  float acc[8][4];
#pragma unroll
  for (int i = 0; i < 8; ++i)
#pragma unroll
    for (int j = 0; j < 4; ++j) acc[i][j] = 0.f;

  for (int k0 = 0; k0 < K; k0 += 64) {
#pragma unroll
    for (int p = 0; p < 4; ++p) {
      int idx = t + p * 256;
      int r = idx >> 4, c4 = idx & 15;
      int gr = m0 + r;
      float4 v = make_float4(0.f, 0.f, 0.f, 0.f);
      if (gr < M) v = *(const float4*)(A + (size_t)gr * lda + k0 + c4 * 4);
      *(float4*)&As[r][c4 * 4] = v;
    }
#pragma unroll
    for (int p = 0; p < 8; ++p) {
      int idx = t + p * 256;
      int r = idx >> 5, c4 = idx & 31;
      float4 v = *(const float4*)(B + (size_t)(k0 + r) * 128 + c4 * 4);
      *(float4*)&Bs[r][c4 * 4] = v;
    }
    __syncthreads();
#pragma unroll
    for (int k = 0; k < 64; ++k) {
      float4 bv = *(float4*)&Bs[k][cg * 4];
#pragma unroll
      for (int i = 0; i < 8; ++i) {
        float av = As[eg * 8 + i][k];
        acc[i][0] += av * bv.x; acc[i][1] += av * bv.y;
        acc[i][2] += av * bv.z; acc[i][3] += av * bv.w;
      }
    }
    __syncthreads();
  }
#pragma unroll
  for (int i = 0; i < 8; ++i) {
    int gr = m0 + eg * 8 + i;
    if (gr < M) {
      float4 v = make_float4(acc[i][0], acc[i][1], acc[i][2], acc[i][3]);
      *(float4*)(C + (size_t)gr * ldc + cg * 4) = v;
    }
  }
}

__device__ inline f16x8 loadAfrag(const _Float16* A, size_t off) {
  return *(const f16x8*)(A + off);
}
__device__ inline f16x8 loadAfrag(const float* A, size_t off) {
  float4 u = *(const float4*)(A + off);
  float4 v = *(const float4*)(A + off + 4);
  return (f16x8){(_Float16)u.x, (_Float16)u.y, (_Float16)u.z, (_Float16)u.w,
                 (_Float16)v.x, (_Float16)v.y, (_Float16)v.z, (_Float16)v.w};
}

// f16 MFMA GEMM body, N=128. MODE 1: CT C plain. MODE 2: f16 C + bias + BN stats.
// lds >= 128*KS*2 + 4096 bytes.
template<int K, int KS, int MODE, typename AT, typename CT>
__device__ void mgemm_body(char* lds, int bid,
                           const AT* __restrict__ A, int lda,
                           const _Float16* __restrict__ BT,
                           CT* __restrict__ C, int ldc, int M,
                           const float* __restrict__ bias, float* __restrict__ bnAcc) {
  const int t = threadIdx.x;
  const int l = t & 63, w = t >> 6;
  const int col0 = l & 15, rg = l >> 4;
  const int rowbase = bid * 256 + w * 64;
  const int sw = (col0 & 7) << 4;

  f32x4 acc[4][8];
  f32x4 zz = {0.f, 0.f, 0.f, 0.f};
#pragma unroll
  for (int a = 0; a < 4; ++a)
#pragma unroll
    for (int n = 0; n < 8; ++n) acc[a][n] = zz;

  for (int ks0 = 0; ks0 < K; ks0 += KS) {
    __syncthreads();
    const int CH = KS / 8;
    for (int u = t; u < 128 * CH; u += 256) {
      int col = u / CH, kc = u % CH;
      f16x8 vch = *(const f16x8*)(BT + (size_t)col * K + ks0 + kc * 8);
      *(f16x8*)(lds + col * (KS * 2) + ((kc * 16) ^ ((col & 7) << 4))) = vch;
    }
    __syncthreads();
#pragma unroll
    for (int ks = 0; ks < KS / 32; ++ks) {
      int kb = ks0 + ks * 32 + rg * 8;
      f16x8 af[4];
#pragma unroll
      for (int a = 0; a < 4; ++a) {
        int rb = rowbase + a * 16;
        if (rb < M) af[a] = loadAfrag(A, (size_t)(rb + col0) * lda + kb);
        else af[a] = (f16x8){0, 0, 0, 0, 0, 0, 0, 0};
      }
      int kc = ks * 4 + rg;
#pragma unroll
      for (int n = 0; n < 8; ++n) {
        f16x8 bf = *(const f16x8*)(lds + (n * 16 + col0) * (KS * 2) + ((kc * 16) ^ sw));
#pragma unroll
        for (int a = 0; a < 4; ++a)
          acc[a][n] = __builtin_amdgcn_mfma_f32_16x16x32_f16(af[a], bf, acc[a][n], 0, 0, 0);
      }
    }
  }

  if (MODE == 1) {
#pragma unroll
    for (int a = 0; a < 4; ++a) {
      int rb = rowbase + a * 16;
      if (rb >= M) continue;
#pragma unroll
      for (int r = 0; r < 4; ++r) {
        int row = rb + rg * 4 + r;
#pragma unroll
        for (int n = 0; n < 8; ++n) {
          int col = n * 16 + col0;
          C[(size_t)row * ldc + col] = (CT)acc[a][n][r];
        }
      }
    }
  } else {
    float sacc[8], qacc[8];
#pragma unroll
    for (int n = 0; n < 8; ++n) { sacc[n] = 0.f; qacc[n] = 0.f; }
#pragma unroll
    for (int a = 0; a < 4; ++a) {
      int rb = rowbase + a * 16;
      if (rb >= M) continue;
#pragma unroll
      for (int n = 0; n < 8; ++n) {
        int col = n * 16 + col0;
        float bi = bias[col];
#pragma unroll
        for (int r = 0; r < 4; ++r) {
          float val = acc[a][n][r] + bi;
          C[(size_t)(rb + rg * 4 + r) * ldc + col] = (CT)val;
          sacc[n] += val; qacc[n] += val * val;
        }
      }
    }
    __syncthreads();
    float* Sb = (float*)lds;
    float* Qb = Sb + 512;
#pragma unroll
    for (int n = 0; n < 8; ++n) {
      float s = sacc[n], q = qacc[n];
      s += __shfl_xor(s, 16); s += __shfl_xor(s, 32);
      q += __shfl_xor(q, 16); q += __shfl_xor(q, 32);
      if (rg == 0) { Sb[w * 128 + n * 16 + col0] = s; Qb[w * 128 + n * 16 + col0] = q; }
    }
    __syncthreads();
    if (t < 128) {
      float s = Sb[t] + Sb[128 + t] + Sb[256 + t] + Sb[384 + t];
      float q = Qb[t] + Qb[128 + t] + Qb[256 + t] + Qb[384 + t];
      atomicAdd(&bnAcc[t], s);
      atomicAdd(&bnAcc[128 + t], q);
    }
  }
}

// merged split body (4 grid-parallel phases). smem >= 3136 bytes.
__device__ void split_body(char* smem, int bid,
                           const int* __restrict__ ei, const int* __restrict__ et,
                           int* __restrict__ gcur,
                           unsigned* __restrict__ recSI, unsigned* __restrict__ recSO,
                           uint2* __restrict__ recDI, uint2* __restrict__ recDO) {
  int* bcnt = (int*)smem;
  int* cnt2 = bcnt + NBUK;
  int* base = cnt2 + NBUK;
  int* nn   = base + NBUK;
  const int t = threadIdx.x;
  const int ph = bid >> 9;
  const int blk = bid & 511;
  const int st = blk * SPAN;
  const int en = min(st + SPAN, EHALF);

  if (t < NBUK) { bcnt[t] = 0; cnt2[t] = 0; }
  __syncthreads();

  if (ph < 2) {
    const int* key = ei + (ph ? EHALF : 0);
    int* gc = gcur + ph * NBUK;
    unsigned* rec = ph ? recSO : recSI;
    unsigned rr[8]; int bb[8];
#pragma unroll
    for (int j = 0; j < 8; ++j) {
      int e = st + j * 256 + t;
      bb[j] = -1;
      if (e < en) {
        int s = key[e];
        rr[j] = (unsigned)(s & 511) | 0x80000000u;
        bb[j] = s >> 9;
        atomicAdd(&bcnt[bb[j]], 1);
      }
    }
    __syncthreads();
    if (t < NBUK) {
      int n = bcnt[t]; nn[t] = n;
      base[t] = n ? (t * SCAP + atomicAdd(&gc[t], (n + 7) & ~7)) : 0;
    }
    __syncthreads();
#pragma unroll
    for (int j = 0; j < 8; ++j) {
      if (bb[j] >= 0) {
        int p = atomicAdd(&cnt2[bb[j]], 1);
        rec[(size_t)base[bb[j]] + p] = rr[j];
      }
    }
    __syncthreads();
    if (t < NBUK) {
      int n = nn[t];
      if (n & 7) {
        int pe = (n + 7) & ~7;
        for (int k = n; k < pe; ++k) rec[(size_t)base[t] + k] = 0u;
      }
    }
  } else {
    const int dir = ph - 2;
    const int* srcA = ei + (dir ? EHALF : 0);
    const int* dstA = ei + (dir ? 3 * EHALF : 2 * EHALF);
    const int* typA = et + (dir ? EHALF : 0);
    int* gc = gcur + (2 + dir) * NBUK;
    uint2* rec = dir ? recDO : recDI;
    unsigned w0[8], w1[8]; int bb[8];
#pragma unroll
    for (int j = 0; j < 8; ++j) {
      int e = st + j * 256 + t;
      bb[j] = -1;
      if (e < en) {
        int s = srcA[e], d = dstA[e], ty = typA[e];
        w0[j] = (unsigned)s | ((unsigned)ty << 17);
        w1[j] = (unsigned)(d & 511) | 0x80000000u;
        bb[j] = d >> 9;
        atomicAdd(&bcnt[bb[j]], 1);
      }
    }
    __syncthreads();
    if (t < NBUK) {
      int n = bcnt[t]; nn[t] = n;
      base[t] = n ? (t * DCAP + atomicAdd(&gc[t], (n + 3) & ~3)) : 0;
    }
    __syncthreads();
#pragma unroll
    for (int j = 0; j < 8; ++j) {
      if (bb[j] >= 0) {
        int p = atomicAdd(&cnt2[bb[j]], 1);
        rec[(size_t)base[bb[j]] + p] = make_uint2(w0[j], w1[j]);
      }
    }
    __syncthreads();
    if (t < NBUK) {
      int n = nn[t];
      if (n & 3) {
        int pe = (n + 3) & ~3;
        for (int k = n; k < pe; ++k) rec[(size_t)base[t] + k] = make_uint2(0u, 0u);
      }
    }
  }
}

// Rf spectra + per-lane pack, 2 rels per 256-thr block. smem >= 1024 bytes.
__device__ void dftrel_body(char* smem, int blk,
                            const float* __restrict__ rel, const float* __restrict__ looprel,
                            const float* __restrict__ Ftab, float* __restrict__ Rf,
                            _Float16* __restrict__ RfL) {
  float* sv = (float*)smem;
  int t = threadIdx.x;
  int r = blk * 2 + (t >> 7);
  int s = t & 127;
  if (r < 501) {
    const float* row = (r < N_REL) ? rel + (size_t)r * 128 : looprel;
    float acc = 0.f;
    for (int n = 0; n < 128; ++n) acc += row[n] * Ftab[n * 128 + s];
    Rf[(size_t)r * 128 + s] = acc;
    sv[t] = acc;
  }
  __syncthreads();
  if (r < 501 && s < 64) {
    int bse = t & 128;
    f16x4 o;
    if (s == 0) {
      o = (f16x4){(_Float16)sv[bse], (_Float16)0.f, (_Float16)0.f, (_Float16)sv[bse + 1]};
    } else {
      float rx = sv[bse + 2 * s], ry = sv[bse + 2 * s + 1];
      o = (f16x4){(_Float16)rx, (_Float16)ry, (_Float16)ry, (_Float16)(-rx)};
    }
    ((f16x4*)RfL)[(size_t)r * 64 + s] = o;
  }
}

// fine sort (512 thr). smem >= 8448 bytes.
__device__ void fsort_body(char* smem, int bid,
                           const uint2* __restrict__ recDI, const int* __restrict__ gDI,
                           uint2* __restrict__ csrIn, int2* __restrict__ beI,
                           const uint2* __restrict__ recDO, const int* __restrict__ gDO,
                           uint2* __restrict__ csrOut, int2* __restrict__ beO,
                           const float* __restrict__ dinvIn, const float* __restrict__ dinvOut) {
  int b = bid % NBUK;
  int dir = bid / NBUK;
  const uint2* rec = dir ? recDO : recDI;
  const int gs = b * DCAP;
  const int ge = gs + (dir ? gDO : gDI)[b];
  const float* dinv = dir ? dinvOut : dinvIn;
  uint2* csr = dir ? csrOut : csrIn;
  int2* be = dir ? beO : beI;
  int* h  = (int*)smem;
  int* sc = h + 512;
  int* c2 = sc + 512;
  float* dl = (float*)(c2 + 512);
  int* totv = (int*)(dl + 512);
  int t = threadIdx.x;
  int ent = b * 512 + t;
  h[t] = 0; c2[t] = 0;
  dl[t] = (ent < N_ENT) ? dinv[ent] : 0.f;
  __syncthreads();
  for (int i = gs + t; i < ge; i += 512) {
    uint2 r = rec[i];
    if (r.y >> 31) atomicAdd(&h[r.y & 511], 1);
  }
  __syncthreads();
  sc[t] = h[t];
  __syncthreads();
  for (int o = 1; o < 512; o <<= 1) {
    int a = (t >= o) ? sc[t - o] : 0;
    __syncthreads();
    sc[t] += a;
    __syncthreads();
  }
  int excl = sc[t] - h[t];
  if (t == 511) *totv = sc[511];
  if (ent < N_ENT) be[ent] = make_int2(gs + excl, gs + excl + h[t]);
  __syncthreads();
  sc[t] = excl;
  __syncthreads();
  if (t < 8) csr[(size_t)gs + *totv + t] = make_uint2(0u, 0u);
  for (int i = gs + t; i < ge; i += 512) {
    uint2 r = rec[i];
    if (r.y >> 31) {
      int d = r.y & 511;
      unsigned src = r.x & 0x1FFFFu;
      float nm = dinv[src] * dl[d];
      H16 cv; cv.h = (_Float16)nm;
      int p = atomicAdd(&c2[d], 1);
      csr[(size_t)gs + sc[d] + p] =
          make_uint2((src * 3u) << 8,                       // src*768 bytes
                     (r.x >> 17) | ((unsigned)cv.u << 16)); // typ | norm<<16
    }
  }
}

// W transpose + loop-rel rotation (512 thr per block)
__device__ void wt_body(int wb, const float* __restrict__ W, const float* __restrict__ Rfl,
                        _Float16* __restrict__ WT) {
  int i = wb * 512 + threadIdx.x;
  if (i >= 384 * 128) return;
  int k = i >> 7, c = i & 127;
  float val;
  if (k < 256) {
    val = W[i];
  } else {
    int kk = k - 256;
    if (kk == 0)      val = Rfl[0] * W[i];
    else if (kk == 1) val = Rfl[1] * W[i];
    else {
      int f = kk >> 1;
      float rr = Rfl[2 * f], ri = Rfl[2 * f + 1];
      float a = W[(256 + 2 * f) * 128 + c];
      float b = W[(256 + 2 * f + 1) * 128 + c];
      val = (kk & 1) ? (ri * a - rr * b) : (rr * a + ri * b);
    }
  }
  WT[(size_t)c * 384 + k] = (_Float16)val;
}

// w_rel transpose to f16 (512 thr per block)
__device__ void wrt_body(int wb, const float* __restrict__ Wr, _Float16* __restrict__ WrT) {
  int i = wb * 512 + threadIdx.x;
  if (i >= 128 * 128) return;
  int k = i >> 7, c = i & 127;
  WrT[(size_t)c * 128 + k] = (_Float16)Wr[i];
}

// ---------------- fused kernels ----------------
// L2: split (4 phases) || rel-DFT  (both low-LDS)
__global__ __launch_bounds__(256) void k_sd(
    const int* __restrict__ ei, const int* __restrict__ et, int* __restrict__ gcur,
    unsigned* __restrict__ recSI, unsigned* __restrict__ recSO,
    uint2* __restrict__ recDI, uint2* __restrict__ recDO,
    const float* __restrict__ rel, const float* __restrict__ looprel,
    const float* __restrict__ Ftab, float* __restrict__ Rf, _Float16* __restrict__ RfL) {
  __shared__ __align__(16) char smem[3200];
  int b = blockIdx.x;
  if (b < 4 * NSB) {
    split_body(smem, b, ei, et, gcur, recSI, recSO, recDI, recDO);
  } else {
    dftrel_body(smem, b - 4 * NSB, rel, looprel, Ftab, Rf, RfL);
  }
}

// L3: Xf-GEMM wrapper (standalone, 37 KB LDS)
__global__ __launch_bounds__(256) void k_xf(
    const float* __restrict__ x, const _Float16* __restrict__ FtabT,
    _Float16* __restrict__ Abuf) {
  __shared__ __align__(16) char lds[36992];
  mgemm_body<128, 128, 1, float, _Float16>(lds, blockIdx.x, x, 128, FtabT,
                                           Abuf + 256, 384, N_ENT, nullptr, nullptr);
}

// L4: Wstack prep GEMMs (standalone)
__global__ __launch_bounds__(256) void k_wprep(
    const float* __restrict__ Gtab, const float* __restrict__ w0,
    const float* __restrict__ w1, const float* __restrict__ w2,
    float* __restrict__ Wstack) {
  __shared__ __align__(16) char smem[49280];
  int which = blockIdx.x >> 1;
  const float* B = (which == 0) ? w0 : ((which == 1) ? w1 : w2);
  gemm128_body(smem, Gtab, 128, B, Wstack + which * 128 * 128, 128, 128, 128,
               (blockIdx.x & 1) * 64);
}

// L5: degree hist -> dinv (standalone, 512 thr)
__global__ __launch_bounds__(512) void k_dhist(
    const unsigned* __restrict__ recI, const int* __restrict__ gI,
    float* __restrict__ dinvIn,
    const unsigned* __restrict__ recO, const int* __restrict__ gO,
    float* __restrict__ dinvOut) {
  int b = blockIdx.x % NBUK;
  int dir = blockIdx.x / NBUK;
  const unsigned* rec = dir ? recO : recI;
  const int gs = b * SCAP;
  const int ge = gs + (dir ? gO : gI)[b];
  float* dinv = dir ? dinvOut : dinvIn;
  __shared__ int h[DPB];
  int t = threadIdx.x;
  h[t] = 0;
  __syncthreads();
  for (int i = gs + t; i < ge; i += 512) {
    unsigned r = rec[i];
    if (r >> 31) atomicAdd(&h[r & 511], 1);
  }
  __syncthreads();
  int ent = b * 512 + t;
  if (ent < N_ENT) {
    int d = h[t];
    dinv[ent] = (d > 0) ? rsqrtf((float)d) : 0.f;
  }
}

// L6: fine sort || WT transpose || w_rel transpose
__global__ __launch_bounds__(512) void k_fw(
    const uint2* __restrict__ recDI, const int* __restrict__ gDI,
    uint2* __restrict__ csrIn, int2* __restrict__ beI,
    const uint2* __restrict__ recDO, const int* __restrict__ gDO,
    uint2* __restrict__ csrOut, int2* __restrict__ beO,
    const float* __restrict__ dinvIn, const float* __restrict__ dinvOut,
    const float* __restrict__ Wstack, const float* __restrict__ Rfl, _Float16* __restrict__ WT,
    const float* __restrict__ w_rel, _Float16* __restrict__ WrT) {
  __shared__ __align__(16) char smem[8448];
  int b = blockIdx.x;
  if (b < 2 * NBUK) {
    fsort_body(smem, b, recDI, gDI, csrIn, beI, recDO, gDO, csrOut, beO, dinvIn, dinvOut);
  } else if (b < 2 * NBUK + 96) {
    wt_body(b - 2 * NBUK, Wstack, Rfl, WT);
  } else {
    wrt_body(b - 2 * NBUK - 96, w_rel, WrT);
  }
}

// L8: output GEMM (MODE 2) || rel_out GEMM (MODE 1, fp32 C)
__global__ __launch_bounds__(256) void k_out(
    const _Float16* __restrict__ Abuf, const _Float16* __restrict__ WT,
    _Float16* __restrict__ tmpC, const float* __restrict__ bias, float* __restrict__ bnAcc,
    const float* __restrict__ rel, const _Float16* __restrict__ WrT, float* __restrict__ out) {
  __shared__ __align__(16) char lds[53504];
  int b = blockIdx.x;
  if (b < XFB) {
    mgemm_body<384, 192, 2, _Float16, _Float16>(lds, b, Abuf, 384, WT, tmpC, 128, N_ENT,
                                                bias, bnAcc);
  } else {
    mgemm_body<128, 128, 1, float, float>(lds, b - XFB, rel, 128, WrT,
                                          out + (size_t)N_ENT * 128, 128, N_REL,
                                          nullptr, nullptr);
  }
}

// L9: BN normalize (standalone, full occupancy)
__global__ void k_norm(const _Float16* __restrict__ tmp, float* __restrict__ out,
                       const float* __restrict__ bnAcc, const float* __restrict__ bnw,
                       const float* __restrict__ bnb) {
  __shared__ float ss[256];
  int t = threadIdx.x;
  if (t < 128) {
    float mu = bnAcc[t] * (1.f / (float)N_ENT);
    float var = bnAcc[128 + t] * (1.f / (float)N_ENT) - mu * mu;
    float sc = bnw[t] * rsqrtf(var + 1e-5f);
    ss[t] = sc; ss[128 + t] = bnb[t] - mu * sc;
  }
  __syncthreads();
  int i = blockIdx.x * 256 + t;
  f16x8 v = ((const f16x8*)tmp)[i];
  int cb = (i & 15) * 8;
  float4 o0, o1;
  o0.x = (float)v[0] * ss[cb]     + ss[128 + cb];
  o0.y = (float)v[1] * ss[cb + 1] + ss[129 + cb];
  o0.z = (float)v[2] * ss[cb + 2] + ss[130 + cb];
  o0.w = (float)v[3] * ss[cb + 3] + ss[131 + cb];
  o1.x = (float)v[4] * ss[cb + 4] + ss[132 + cb];
  o1.y = (float)v[5] * ss[cb + 5] + ss[133 + cb];
  o1.z = (float)v[6] * ss[cb + 6] + ss[134 + cb];
  o1.w = (float)v[7] * ss[cb + 7] + ss[135 + cb];
  ((float4*)out)[2 * i] = o0;
  ((float4*)out)[2 * i + 1] = o1;
}

// ---------------- L7: frequency-domain edge aggregation ----------------
__device__ inline float dot2f(f16x2 a, f16x2 b, float c) {
#if __has_builtin(__builtin_amdgcn_fdot2)
  return __builtin_amdgcn_fdot2(a, b, c, false);
#else
  return fmaf((float)a[0], (float)b[0], fmaf((float)a[1], (float)b[1], c));
#endif
}

__device__ inline void b4load(const uint2* __restrict__ csr, int base,
                              const char* __restrict__ Xb, const char* __restrict__ Rb,
                              unsigned lxc, unsigned lr,
                              uint2 q[4], f16x2 xv[4], f16x4 rv[4]) {
#pragma unroll
  for (int j = 0; j < 4; ++j) q[j] = csr[base + j];
#pragma unroll
  for (int j = 0; j < 4; ++j) {
    xv[j] = *(const f16x2*)(Xb + q[j].x + lxc);
    rv[j] = *(const f16x4*)(Rb + ((q[j].y & 0x1FFu) << 9) + lr);
  }
}
__device__ inline void b4math(const uint2 q[4], int base, int end,
                              const f16x2 xv[4], const f16x4 rv[4],
                              float& ax, float& ay) {
#pragma unroll
  for (int j = 0; j < 4; ++j) {
    unsigned nb = (base + j < end) ? (q[j].y >> 16) : 0u;
    HU32 nm; nm.u = nb | (nb << 16);
    f16x2 xs = xv[j] * nm.h;
    ax = dot2f(xs, (f16x2){rv[j][0], rv[j][1]}, ax);
    ay = dot2f(xs, (f16x2){rv[j][2], rv[j][3]}, ay);
  }
}

__global__ __launch_bounds__(256) void k_agg(
    _Float16* __restrict__ Abuf, const _Float16* __restrict__ RfL,
    const uint2* __restrict__ csrIn, const int2* __restrict__ beI,
    const uint2* __restrict__ csrOut, const int2* __restrict__ beO) {
  const int w = threadIdx.x >> 6, l = threadIdx.x & 63;
  const int v = blockIdx.x * 4 + w;
  const char* Xb = (const char*)Abuf;
  const char* Rb = (const char*)RfL;
  const unsigned lxc = 512u + (unsigned)l * 4u;
  const unsigned lr = (unsigned)l * 8u;
  int2 bi = beI[v], bo = beO[v];
  int i  = __builtin_amdgcn_readfirstlane(bi.x);
  int ie = __builtin_amdgcn_readfirstlane(bi.y);
  int o  = __builtin_amdgcn_readfirstlane(bo.x);
  int oe = __builtin_amdgcn_readfirstlane(bo.y);
  int nbi = (ie - i + 3) >> 2;
  int nbo = (oe - o + 3) >> 2;
  float aix = 0.f, aiy = 0.f, aox = 0.f, aoy = 0.f;

  while (nbi > 0 && nbo > 0) {
    uint2 qa[4], qb[4]; f16x2 xa[4], xb[4]; f16x4 ra[4], rb[4];
    b4load(csrIn, i, Xb, Rb, lxc, lr, qa, xa, ra);
    b4load(csrOut, o, Xb, Rb, lxc, lr, qb, xb, rb);
    b4math(qa, i, ie, xa, ra, aix, aiy);
    b4math(qb, o, oe, xb, rb, aox, aoy);
    i += 4; o += 4; --nbi; --nbo;
  }
  while (nbi > 0) {
    uint2 qa[4]; f16x2 xa[4]; f16x4 ra[4];
    b4load(csrIn, i, Xb, Rb, lxc, lr, qa, xa, ra);
    b4math(qa, i, ie, xa, ra, aix, aiy);
    i += 4; --nbi;
  }
  while (nbo > 0) {
    uint2 qb[4]; f16x2 xb[4]; f16x4 rb[4];
    b4load(csrOut, o, Xb, Rb, lxc, lr, qb, xb, rb);
    b4math(qb, o, oe, xb, rb, aox, aoy);
    o += 4; --nbo;
  }

  *(f16x2*)((char*)Abuf + (size_t)v * 768 + 4u * l) = (f16x2){(_Float16)aix, (_Float16)aiy};
  *(f16x2*)((char*)Abuf + (size_t)v * 768 + 256 + 4u * l) = (f16x2){(_Float16)aox, (_Float16)aoy};
}

extern "C" void kernel_launch(void* const* d_in, const int* in_sizes, int n_in,
                              void* d_out, int out_size, void* d_ws, size_t ws_size,
                              hipStream_t stream) {
  const float* x       = (const float*)d_in[0];
  const float* rel     = (const float*)d_in[1];
  const float* w_in    = (const float*)d_in[2];
  const float* w_out   = (const float*)d_in[3];
  const float* w_loop  = (const float*)d_in[4];
  const float* w_rel   = (const float*)d_in[5];
  const float* looprel = (const float*)d_in[6];
  const float* bias    = (const float*)d_in[7];
  const float* bnw     = (const float*)d_in[8];
  const float* bnb     = (const float*)d_in[9];
  const int*   ei      = (const int*)d_in[10];
  const int*   et      = (const int*)d_in[11];
  float* out = (float*)d_out;

  char* p = (char*)d_ws;
  auto alloc = [&](size_t bytes) -> void* {
    void* r = (void*)p;
    p += (bytes + 255) & ~(size_t)255;
    return r;
  };
  _Float16* Abuf  = (_Float16*)alloc((size_t)N_ENT * 384 * 2);
  _Float16* tmpC  = (_Float16*)alloc((size_t)N_ENT * 128 * 2);
  _Float16* WT    = (_Float16*)alloc(128 * 384 * 2);
  _Float16* WrT   = (_Float16*)alloc(128 * 128 * 2);
  _Float16* FtabT = (_Float16*)alloc(128 * 128 * 2);
  _Float16* RfL   = (_Float16*)alloc(501 * 64 * 4 * 2);
  float* Wstack   = (float*)alloc(384 * 128 * 4);
  float* Ftab     = (float*)alloc(128 * 128 * 4);
  float* Gtab     = (float*)alloc(128 * 128 * 4);
  float* Rf       = (float*)alloc(501 * 128 * 4);
  float* dinvIn   = (float*)alloc(N_ENT * 4);
  float* dinvOut  = (float*)alloc(N_ENT * 4);
  int*   gcur     = (int*)alloc(4 * NBUK * 4);   // gSI|gSO|gDI|gDO (relative)
  int2*  beI      = (int2*)alloc((size_t)N_ENT * 8);
  int2*  beO      = (int2*)alloc((size_t)N_ENT * 8);
  unsigned* recSI = (unsigned*)alloc((size_t)NBUK * SCAP * 4);
  unsigned* recSO = (unsigned*)alloc((size_t)NBUK * SCAP * 4);
  uint2* recDI    = (uint2*)alloc((size_t)NBUK * DCAP * 8);
  uint2* recDO    = (uint2*)alloc((size_t)NBUK * DCAP * 8);
  uint2* csrIn    = (uint2*)alloc((size_t)NBUK * DCAP * 8);
  uint2* csrOut   = (uint2*)alloc((size_t)NBUK * DCAP * 8);
  float* bnAcc    = (float*)alloc(256 * 4);

  int* gSI = gcur;
  int* gSO = gcur + NBUK;
  int* gDI = gcur + 2 * NBUK;
  int* gDO = gcur + 3 * NBUK;

  // L1: tables + cursor/bnAcc zeroing
  k_tabs<<<64, 256, 0, stream>>>(Ftab, Gtab, FtabT, gcur, bnAcc);

  // L2: split (4 phases) || rel-DFT
  k_sd<<<4 * NSB + 251, 256, 0, stream>>>(ei, et, gcur, recSI, recSO, recDI, recDO,
                                          rel, looprel, Ftab, Rf, RfL);

  // L3: Xf = rfft(x) via f16 MFMA into Abuf cols [256..384)
  k_xf<<<XFB, 256, 0, stream>>>(x, FtabT, Abuf);

  // L4: Wstack prep GEMMs
  k_wprep<<<6, 256, 0, stream>>>(Gtab, w_in, w_out, w_loop, Wstack);

  // L5: degrees -> dinv
  k_dhist<<<2 * NBUK, 512, 0, stream>>>(recSI, gSI, dinvIn, recSO, gSO, dinvOut);

  // L6: fine sort -> CSR || WT transpose (+rotation) || w_rel transpose
  k_fw<<<2 * NBUK + 96 + 32, 512, 0, stream>>>(
      recDI, gDI, csrIn, beI, recDO, gDO, csrOut, beO, dinvIn, dinvOut,
      Wstack, Rf + 500 * 128, WT, w_rel, WrT);

  // L7: frequency-domain aggregation
  k_agg<<<N_ENT / 4, 256, 0, stream>>>(Abuf, RfL, csrIn, beI, csrOut, beO);

  // L8: output GEMM + bias -> f16 tmp + BN stats || rel_out GEMM (fp32 C)
  k_out<<<XFB + 2, 256, 0, stream>>>(Abuf, WT, tmpC, bias, bnAcc, rel, WrT, out);

  // L9: BN normalize -> fp32 out
  k_norm<<<(N_ENT * 128 / 8) / 256, 256, 0, stream>>>(tmpC, out, bnAcc, bnw, bnb);
}

// Round 14
// 298.473 us; speedup vs baseline: 1.1005x; 1.0024x over previous
//
#include <hip/hip_runtime.h>
#include <cmath>

#define N_ENT 100000
#define EHALF 1000000
#define N_REL 500
#define NBUK 196          // ceil(100000/512) coarse buckets (key>>9)
#define DPB 512           // entities per bucket
#define SCAP 7680         // src-record region capacity per bucket (4B recs)
#define DCAP 6656         // dst-record / csr region capacity per bucket (8B recs)
#define NSB 512           // split blocks per phase
#define SPAN 1954         // ceil(EHALF/NSB)
#define XFB 391           // ceil(N_ENT/256) MFMA-gemm blocks

#ifndef M_PI
#define M_PI 3.14159265358979323846
#endif

typedef _Float16 f16x8 __attribute__((ext_vector_type(8)));
typedef _Float16 f16x4 __attribute__((ext_vector_type(4)));
typedef _Float16 f16x2 __attribute__((ext_vector_type(2)));
typedef float f32x4 __attribute__((ext_vector_type(4)));

union H16 { unsigned short u; _Float16 h; };
union HU32 { unsigned u; f16x2 h; };

// ---------------- L1: DFT tables + cursor/bnAcc zeroing ----------------
__global__ void k_tabs(float* __restrict__ Ftab, float* __restrict__ Gtab,
                       _Float16* __restrict__ FtabT,
                       int* __restrict__ gcur, float* __restrict__ bnAcc) {
  if (blockIdx.x == 0) {
    for (int j = threadIdx.x; j < 4 * NBUK; j += 256) gcur[j] = 0;
    bnAcc[threadIdx.x] = 0.f;
  }
  int i = blockIdx.x * 256 + threadIdx.x;
  if (i >= 128 * 128) return;
  int n = i >> 7, s = i & 127;
  float fv, gv;
  if (s == 0) { fv = 1.f; gv = 1.f / 384.f; }
  else if (s == 1) { float sg = (n & 1) ? -1.f : 1.f; fv = sg; gv = sg / 384.f; }
  else {
    int f = s >> 1;
    double ang = 2.0 * M_PI * (double)((f * n) & 127) / 128.0;
    if (!(s & 1)) { double c = cos(ang); fv = (float)c; gv = (float)(c * (2.0 / 384.0)); }
    else { double sv = sin(ang); fv = (float)(-sv); gv = (float)(-sv * (2.0 / 384.0)); }
  }
  Ftab[n * 128 + s] = fv;
  Gtab[s * 128 + n] = gv;
  FtabT[s * 128 + n] = (_Float16)fv;
}

// ---------------- device bodies ----------------
// fp32 GEMM body, N fixed = 128 (prep GEMMs). smem >= 49152 bytes.
__device__ void gemm128_body(char* smem, const float* __restrict__ A, int lda,
                             const float* __restrict__ B,
                             float* __restrict__ C, int ldc,
                             int M, int K, int m0) {
  float (*As)[64] = (float(*)[64])smem;
  float (*Bs)[128] = (float(*)[128])(smem + 64 * 64 * 4);
  const int t = threadIdx.x;
  const int cg = t & 31;
  const int eg = t >> 5;
  float acc[8][4];
#pragma unroll
  for (int i = 0; i < 8; ++i)
#pragma unroll
    for (int j = 0; j < 4; ++j) acc[i][j] = 0.f;

  for (int k0 = 0; k0 < K; k0 += 64) {
#pragma unroll
    for (int p = 0; p < 4; ++p) {
      int idx = t + p * 256;
      int r = idx >> 4, c4 = idx & 15;
      int gr = m0 + r;
      float4 v = make_float4(0.f, 0.f, 0.f, 0.f);
      if (gr < M) v = *(const float4*)(A + (size_t)gr * lda + k0 + c4 * 4);
      *(float4*)&As[r][c4 * 4] = v;
    }
#pragma unroll
    for (int p = 0; p < 8; ++p) {
      int idx = t + p * 256;
      int r = idx >> 5, c4 = idx & 31;
      float4 v = *(const float4*)(B + (size_t)(k0 + r) * 128 + c4 * 4);
      *(float4*)&Bs[r][c4 * 4] = v;
    }
    __syncthreads();
#pragma unroll
    for (int k = 0; k < 64; ++k) {
      float4 bv = *(float4*)&Bs[k][cg * 4];
#pragma unroll
      for (int i = 0; i < 8; ++i) {
        float av = As[eg * 8 + i][k];
        acc[i][0] += av * bv.x; acc[i][1] += av * bv.y;
        acc[i][2] += av * bv.z; acc[i][3] += av * bv.w;
      }
    }
    __syncthreads();
  }
#pragma unroll
  for (int i = 0; i < 8; ++i) {
    int gr = m0 + eg * 8 + i;
    if (gr < M) {
      float4 v = make_float4(acc[i][0], acc[i][1], acc[i][2], acc[i][3]);
      *(float4*)(C + (size_t)gr * ldc + cg * 4) = v;
    }
  }
}

__device__ inline f16x8 loadAfrag(const _Float16* A, size_t off) {
  return *(const f16x8*)(A + off);
}
__device__ inline f16x8 loadAfrag(const float* A, size_t off) {
  float4 u = *(const float4*)(A + off);
  float4 v = *(const float4*)(A + off + 4);
  return (f16x8){(_Float16)u.x, (_Float16)u.y, (_Float16)u.z, (_Float16)u.w,
                 (_Float16)v.x, (_Float16)v.y, (_Float16)v.z, (_Float16)v.w};
}

// f16 MFMA GEMM body, N=128. MODE 1: CT C plain. MODE 2: f16 C + bias + BN stats.
// lds >= 128*KS*2 + 4096 bytes.
template<int K, int KS, int MODE, typename AT, typename CT>
__device__ void mgemm_body(char* lds, int bid,
                           const AT* __restrict__ A, int lda,
                           const _Float16* __restrict__ BT,
                           CT* __restrict__ C, int ldc, int M,
                           const float* __restrict__ bias, float* __restrict__ bnAcc) {
  const int t = threadIdx.x;
  const int l = t & 63, w = t >> 6;
  const int col0 = l & 15, rg = l >> 4;
  const int rowbase = bid * 256 + w * 64;
  const int sw = (col0 & 7) << 4;

  f32x4 acc[4][8];
  f32x4 zz = {0.f, 0.f, 0.f, 0.f};
#pragma unroll
  for (int a = 0; a < 4; ++a)
#pragma unroll
    for (int n = 0; n < 8; ++n) acc[a][n] = zz;

  for (int ks0 = 0; ks0 < K; ks0 += KS) {
    __syncthreads();
    const int CH = KS / 8;
    for (int u = t; u < 128 * CH; u += 256) {
      int col = u / CH, kc = u % CH;
      f16x8 vch = *(const f16x8*)(BT + (size_t)col * K + ks0 + kc * 8);
      *(f16x8*)(lds + col * (KS * 2) + ((kc * 16) ^ ((col & 7) << 4))) = vch;
    }
    __syncthreads();
#pragma unroll
    for (int ks = 0; ks < KS / 32; ++ks) {
      int kb = ks0 + ks * 32 + rg * 8;
      f16x8 af[4];
#pragma unroll
      for (int a = 0; a < 4; ++a) {
        int rb = rowbase + a * 16;
        if (rb < M) af[a] = loadAfrag(A, (size_t)(rb + col0) * lda + kb);
        else af[a] = (f16x8){0, 0, 0, 0, 0, 0, 0, 0};
      }
      int kc = ks * 4 + rg;
#pragma unroll
      for (int n = 0; n < 8; ++n) {
        f16x8 bf = *(const f16x8*)(lds + (n * 16 + col0) * (KS * 2) + ((kc * 16) ^ sw));
#pragma unroll
        for (int a = 0; a < 4; ++a)
          acc[a][n] = __builtin_amdgcn_mfma_f32_16x16x32_f16(af[a], bf, acc[a][n], 0, 0, 0);
      }
    }
  }

  if (MODE == 1) {
#pragma unroll
    for (int a = 0; a < 4; ++a) {
      int rb = rowbase + a * 16;
      if (rb >= M) continue;
#pragma unroll
      for (int r = 0; r < 4; ++r) {
        int row = rb + rg * 4 + r;
#pragma unroll
        for (int n = 0; n < 8; ++n) {
          int col = n * 16 + col0;
          C[(size_t)row * ldc + col] = (CT)acc[a][n][r];
        }
      }
    }
  } else {
    float sacc[8], qacc[8];
#pragma unroll
    for (int n = 0; n < 8; ++n) { sacc[n] = 0.f; qacc[n] = 0.f; }
#pragma unroll
    for (int a = 0; a < 4; ++a) {
      int rb = rowbase + a * 16;
      if (rb >= M) continue;
#pragma unroll
      for (int n = 0; n < 8; ++n) {
        int col = n * 16 + col0;
        float bi = bias[col];
#pragma unroll
        for (int r = 0; r < 4; ++r) {
          float val = acc[a][n][r] + bi;
          C[(size_t)(rb + rg * 4 + r) * ldc + col] = (CT)val;
          sacc[n] += val; qacc[n] += val * val;
        }
      }
    }
    __syncthreads();
    float* Sb = (float*)lds;
    float* Qb = Sb + 512;
#pragma unroll
    for (int n = 0; n < 8; ++n) {
      float s = sacc[n], q = qacc[n];
      s += __shfl_xor(s, 16); s += __shfl_xor(s, 32);
      q += __shfl_xor(q, 16); q += __shfl_xor(q, 32);
      if (rg == 0) { Sb[w * 128 + n * 16 + col0] = s; Qb[w * 128 + n * 16 + col0] = q; }
    }
    __syncthreads();
    if (t < 128) {
      float s = Sb[t] + Sb[128 + t] + Sb[256 + t] + Sb[384 + t];
      float q = Qb[t] + Qb[128 + t] + Qb[256 + t] + Qb[384 + t];
      atomicAdd(&bnAcc[t], s);
      atomicAdd(&bnAcc[128 + t], q);
    }
  }
}

// merged split body (4 grid-parallel phases). smem >= 3136 bytes.
__device__ void split_body(char* smem, int bid,
                           const int* __restrict__ ei, const int* __restrict__ et,
                           int* __restrict__ gcur,
                           unsigned* __restrict__ recSI, unsigned* __restrict__ recSO,
                           uint2* __restrict__ recDI, uint2* __restrict__ recDO) {
  int* bcnt = (int*)smem;
  int* cnt2 = bcnt + NBUK;
  int* base = cnt2 + NBUK;
  int* nn   = base + NBUK;
  const int t = threadIdx.x;
  const int ph = bid >> 9;
  const int blk = bid & 511;
  const int st = blk * SPAN;
  const int en = min(st + SPAN, EHALF);

  if (t < NBUK) { bcnt[t] = 0; cnt2[t] = 0; }
  __syncthreads();

  if (ph < 2) {
    const int* key = ei + (ph ? EHALF : 0);
    int* gc = gcur + ph * NBUK;
    unsigned* rec = ph ? recSO : recSI;
    unsigned rr[8]; int bb[8];
#pragma unroll
    for (int j = 0; j < 8; ++j) {
      int e = st + j * 256 + t;
      bb[j] = -1;
      if (e < en) {
        int s = key[e];
        rr[j] = (unsigned)(s & 511) | 0x80000000u;
        bb[j] = s >> 9;
        atomicAdd(&bcnt[bb[j]], 1);
      }
    }
    __syncthreads();
    if (t < NBUK) {
      int n = bcnt[t]; nn[t] = n;
      base[t] = n ? (t * SCAP + atomicAdd(&gc[t], (n + 7) & ~7)) : 0;
    }
    __syncthreads();
#pragma unroll
    for (int j = 0; j < 8; ++j) {
      if (bb[j] >= 0) {
        int p = atomicAdd(&cnt2[bb[j]], 1);
        rec[(size_t)base[bb[j]] + p] = rr[j];
      }
    }
    __syncthreads();
    if (t < NBUK) {
      int n = nn[t];
      if (n & 7) {
        int pe = (n + 7) & ~7;
        for (int k = n; k < pe; ++k) rec[(size_t)base[t] + k] = 0u;
      }
    }
  } else {
    const int dir = ph - 2;
    const int* srcA = ei + (dir ? EHALF : 0);
    const int* dstA = ei + (dir ? 3 * EHALF : 2 * EHALF);
    const int* typA = et + (dir ? EHALF : 0);
    int* gc = gcur + (2 + dir) * NBUK;
    uint2* rec = dir ? recDO : recDI;
    unsigned w0[8], w1[8]; int bb[8];
#pragma unroll
    for (int j = 0; j < 8; ++j) {
      int e = st + j * 256 + t;
      bb[j] = -1;
      if (e < en) {
        int s = srcA[e], d = dstA[e], ty = typA[e];
        w0[j] = (unsigned)s | ((unsigned)ty << 17);
        w1[j] = (unsigned)(d & 511) | 0x80000000u;
        bb[j] = d >> 9;
        atomicAdd(&bcnt[bb[j]], 1);
      }
    }
    __syncthreads();
    if (t < NBUK) {
      int n = bcnt[t]; nn[t] = n;
      base[t] = n ? (t * DCAP + atomicAdd(&gc[t], (n + 3) & ~3)) : 0;
    }
    __syncthreads();
#pragma unroll
    for (int j = 0; j < 8; ++j) {
      if (bb[j] >= 0) {
        int p = atomicAdd(&cnt2[bb[j]], 1);
        rec[(size_t)base[bb[j]] + p] = make_uint2(w0[j], w1[j]);
      }
    }
    __syncthreads();
    if (t < NBUK) {
      int n = nn[t];
      if (n & 3) {
        int pe = (n + 3) & ~3;
        for (int k = n; k < pe; ++k) rec[(size_t)base[t] + k] = make_uint2(0u, 0u);
      }
    }
  }
}

// Rf spectra + per-lane pack, 2 rels per 256-thr block. smem >= 1024 bytes.
__device__ void dftrel_body(char* smem, int blk,
                            const float* __restrict__ rel, const float* __restrict__ looprel,
                            const float* __restrict__ Ftab, float* __restrict__ Rf,
                            _Float16* __restrict__ RfL) {
  float* sv = (float*)smem;
  int t = threadIdx.x;
  int r = blk * 2 + (t >> 7);
  int s = t & 127;
  if (r < 501) {
    const float* row = (r < N_REL) ? rel + (size_t)r * 128 : looprel;
    float acc = 0.f;
    for (int n = 0; n < 128; ++n) acc += row[n] * Ftab[n * 128 + s];
    Rf[(size_t)r * 128 + s] = acc;
    sv[t] = acc;
  }
  __syncthreads();
  if (r < 501 && s < 64) {
    int bse = t & 128;
    f16x4 o;
    if (s == 0) {
      o = (f16x4){(_Float16)sv[bse], (_Float16)0.f, (_Float16)0.f, (_Float16)sv[bse + 1]};
    } else {
      float rx = sv[bse + 2 * s], ry = sv[bse + 2 * s + 1];
      o = (f16x4){(_Float16)rx, (_Float16)ry, (_Float16)ry, (_Float16)(-rx)};
    }
    ((f16x4*)RfL)[(size_t)r * 64 + s] = o;
  }
}

// fine sort (512 thr). smem >= 8448 bytes.
__device__ void fsort_body(char* smem, int bid,
                           const uint2* __restrict__ recDI, const int* __restrict__ gDI,
                           uint2* __restrict__ csrIn, int2* __restrict__ beI,
                           const uint2* __restrict__ recDO, const int* __restrict__ gDO,
                           uint2* __restrict__ csrOut, int2* __restrict__ beO,
                           const float* __restrict__ dinvIn, const float* __restrict__ dinvOut) {
  int b = bid % NBUK;
  int dir = bid / NBUK;
  const uint2* rec = dir ? recDO : recDI;
  const int gs = b * DCAP;
  const int ge = gs + (dir ? gDO : gDI)[b];
  const float* dinv = dir ? dinvOut : dinvIn;
  uint2* csr = dir ? csrOut : csrIn;
  int2* be = dir ? beO : beI;
  int* h  = (int*)smem;
  int* sc = h + 512;
  int* c2 = sc + 512;
  float* dl = (float*)(c2 + 512);
  int* totv = (int*)(dl + 512);
  int t = threadIdx.x;
  int ent = b * 512 + t;
  h[t] = 0; c2[t] = 0;
  dl[t] = (ent < N_ENT) ? dinv[ent] : 0.f;
  __syncthreads();
  for (int i = gs + t; i < ge; i += 512) {
    uint2 r = rec[i];
    if (r.y >> 31) atomicAdd(&h[r.y & 511], 1);
  }
  __syncthreads();
  sc[t] = h[t];
  __syncthreads();
  for (int o = 1; o < 512; o <<= 1) {
    int a = (t >= o) ? sc[t - o] : 0;
    __syncthreads();
    sc[t] += a;
    __syncthreads();
  }
  int excl = sc[t] - h[t];
  if (t == 511) *totv = sc[511];
  if (ent < N_ENT) be[ent] = make_int2(gs + excl, gs + excl + h[t]);
  __syncthreads();
  sc[t] = excl;
  __syncthreads();
  if (t < 8) csr[(size_t)gs + *totv + t] = make_uint2(0u, 0u);
  for (int i = gs + t; i < ge; i += 512) {
    uint2 r = rec[i];
    if (r.y >> 31) {
      int d = r.y & 511;
      unsigned src = r.x & 0x1FFFFu;
      float nm = dinv[src] * dl[d];
      H16 cv; cv.h = (_Float16)nm;
      int p = atomicAdd(&c2[d], 1);
      csr[(size_t)gs + sc[d] + p] =
          make_uint2((src * 3u) << 8,                       // src*768 bytes
                     (r.x >> 17) | ((unsigned)cv.u << 16)); // typ | norm<<16
    }
  }
}

// W transpose + loop-rel rotation (512 thr per block)
__device__ void wt_body(int wb, const float* __restrict__ W, const float* __restrict__ Rfl,
                        _Float16* __restrict__ WT) {
  int i = wb * 512 + threadIdx.x;
  if (i >= 384 * 128) return;
  int k = i >> 7, c = i & 127;
  float val;
  if (k < 256) {
    val = W[i];
  } else {
    int kk = k - 256;
    if (kk == 0)      val = Rfl[0] * W[i];
    else if (kk == 1) val = Rfl[1] * W[i];
    else {
      int f = kk >> 1;
      float rr = Rfl[2 * f], ri = Rfl[2 * f + 1];
      float a = W[(256 + 2 * f) * 128 + c];
      float b = W[(256 + 2 * f + 1) * 128 + c];
      val = (kk & 1) ? (ri * a - rr * b) : (rr * a + ri * b);
    }
  }
  WT[(size_t)c * 384 + k] = (_Float16)val;
}

// w_rel transpose to f16 (512 thr per block)
__device__ void wrt_body(int wb, const float* __restrict__ Wr, _Float16* __restrict__ WrT) {
  int i = wb * 512 + threadIdx.x;
  if (i >= 128 * 128) return;
  int k = i >> 7, c = i & 127;
  WrT[(size_t)c * 128 + k] = (_Float16)Wr[i];
}

// ---------------- fused kernels ----------------
// L2: split (4 phases) || rel-DFT  (both low-LDS)
__global__ __launch_bounds__(256) void k_sd(
    const int* __restrict__ ei, const int* __restrict__ et, int* __restrict__ gcur,
    unsigned* __restrict__ recSI, unsigned* __restrict__ recSO,
    uint2* __restrict__ recDI, uint2* __restrict__ recDO,
    const float* __restrict__ rel, const float* __restrict__ looprel,
    const float* __restrict__ Ftab, float* __restrict__ Rf, _Float16* __restrict__ RfL) {
  __shared__ __align__(16) char smem[3200];
  int b = blockIdx.x;
  if (b < 4 * NSB) {
    split_body(smem, b, ei, et, gcur, recSI, recSO, recDI, recDO);
  } else {
    dftrel_body(smem, b - 4 * NSB, rel, looprel, Ftab, Rf, RfL);
  }
}

// L3: Xf-GEMM wrapper (standalone, 37 KB LDS)
__global__ __launch_bounds__(256) void k_xf(
    const float* __restrict__ x, const _Float16* __restrict__ FtabT,
    _Float16* __restrict__ Abuf) {
  __shared__ __align__(16) char lds[36992];
  mgemm_body<128, 128, 1, float, _Float16>(lds, blockIdx.x, x, 128, FtabT,
                                           Abuf + 256, 384, N_ENT, nullptr, nullptr);
}

// L4: Wstack prep GEMMs (standalone)
__global__ __launch_bounds__(256) void k_wprep(
    const float* __restrict__ Gtab, const float* __restrict__ w0,
    const float* __restrict__ w1, const float* __restrict__ w2,
    float* __restrict__ Wstack) {
  __shared__ __align__(16) char smem[49280];
  int which = blockIdx.x >> 1;
  const float* B = (which == 0) ? w0 : ((which == 1) ? w1 : w2);
  gemm128_body(smem, Gtab, 128, B, Wstack + which * 128 * 128, 128, 128, 128,
               (blockIdx.x & 1) * 64);
}

// L5: degree hist -> dinv (standalone, 512 thr)
__global__ __launch_bounds__(512) void k_dhist(
    const unsigned* __restrict__ recI, const int* __restrict__ gI,
    float* __restrict__ dinvIn,
    const unsigned* __restrict__ recO, const int* __restrict__ gO,
    float* __restrict__ dinvOut) {
  int b = blockIdx.x % NBUK;
  int dir = blockIdx.x / NBUK;
  const unsigned* rec = dir ? recO : recI;
  const int gs = b * SCAP;
  const int ge = gs + (dir ? gO : gI)[b];
  float* dinv = dir ? dinvOut : dinvIn;
  __shared__ int h[DPB];
  int t = threadIdx.x;
  h[t] = 0;
  __syncthreads();
  for (int i = gs + t; i < ge; i += 512) {
    unsigned r = rec[i];
    if (r >> 31) atomicAdd(&h[r & 511], 1);
  }
  __syncthreads();
  int ent = b * 512 + t;
  if (ent < N_ENT) {
    int d = h[t];
    dinv[ent] = (d > 0) ? rsqrtf((float)d) : 0.f;
  }
}

// L6: fine sort || WT transpose || w_rel transpose
__global__ __launch_bounds__(512) void k_fw(
    const uint2* __restrict__ recDI, const int* __restrict__ gDI,
    uint2* __restrict__ csrIn, int2* __restrict__ beI,
    const uint2* __restrict__ recDO, const int* __restrict__ gDO,
    uint2* __restrict__ csrOut, int2* __restrict__ beO,
    const float* __restrict__ dinvIn, const float* __restrict__ dinvOut,
    const float* __restrict__ Wstack, const float* __restrict__ Rfl, _Float16* __restrict__ WT,
    const float* __restrict__ w_rel, _Float16* __restrict__ WrT) {
  __shared__ __align__(16) char smem[8448];
  int b = blockIdx.x;
  if (b < 2 * NBUK) {
    fsort_body(smem, b, recDI, gDI, csrIn, beI, recDO, gDO, csrOut, beO, dinvIn, dinvOut);
  } else if (b < 2 * NBUK + 96) {
    wt_body(b - 2 * NBUK, Wstack, Rfl, WT);
  } else {
    wrt_body(b - 2 * NBUK - 96, w_rel, WrT);
  }
}

// L8: output GEMM (MODE 2) || rel_out GEMM (MODE 1, fp32 C)
__global__ __launch_bounds__(256) void k_out(
    const _Float16* __restrict__ Abuf, const _Float16* __restrict__ WT,
    _Float16* __restrict__ tmpC, const float* __restrict__ bias, float* __restrict__ bnAcc,
    const float* __restrict__ rel, const _Float16* __restrict__ WrT, float* __restrict__ out) {
  __shared__ __align__(16) char lds[53504];
  int b = blockIdx.x;
  if (b < XFB) {
    mgemm_body<384, 192, 2, _Float16, _Float16>(lds, b, Abuf, 384, WT, tmpC, 128, N_ENT,
                                                bias, bnAcc);
  } else {
    mgemm_body<128, 128, 1, float, float>(lds, b - XFB, rel, 128, WrT,
                                          out + (size_t)N_ENT * 128, 128, N_REL,
                                          nullptr, nullptr);
  }
}

// L9: BN normalize (standalone, full occupancy)
__global__ void k_norm(const _Float16* __restrict__ tmp, float* __restrict__ out,
                       const float* __restrict__ bnAcc, const float* __restrict__ bnw,
                       const float* __restrict__ bnb) {
  __shared__ float ss[256];
  int t = threadIdx.x;
  if (t < 128) {
    float mu = bnAcc[t] * (1.f / (float)N_ENT);
    float var = bnAcc[128 + t] * (1.f / (float)N_ENT) - mu * mu;
    float sc = bnw[t] * rsqrtf(var + 1e-5f);
    ss[t] = sc; ss[128 + t] = bnb[t] - mu * sc;
  }
  __syncthreads();
  int i = blockIdx.x * 256 + t;
  f16x8 v = ((const f16x8*)tmp)[i];
  int cb = (i & 15) * 8;
  float4 o0, o1;
  o0.x = (float)v[0] * ss[cb]     + ss[128 + cb];
  o0.y = (float)v[1] * ss[cb + 1] + ss[129 + cb];
  o0.z = (float)v[2] * ss[cb + 2] + ss[130 + cb];
  o0.w = (float)v[3] * ss[cb + 3] + ss[131 + cb];
  o1.x = (float)v[4] * ss[cb + 4] + ss[132 + cb];
  o1.y = (float)v[5] * ss[cb + 5] + ss[133 + cb];
  o1.z = (float)v[6] * ss[cb + 6] + ss[134 + cb];
  o1.w = (float)v[7] * ss[cb + 7] + ss[135 + cb];
  ((float4*)out)[2 * i] = o0;
  ((float4*)out)[2 * i + 1] = o1;
}

// ---------------- L7: frequency-domain edge aggregation ----------------
__device__ inline float dot2f(f16x2 a, f16x2 b, float c) {
#if __has_builtin(__builtin_amdgcn_fdot2)
  return __builtin_amdgcn_fdot2(a, b, c, false);
#else
  return fmaf((float)a[0], (float)b[0], fmaf((float)a[1], (float)b[1], c));
#endif
}

// software-pipelined 4-edge batches: rec loads for batch k+1 issue while
// batch k's X/R gathers and math are in flight. Over-read of <=4 records past
// an entity end lands in valid following records or the 8 zero-pad records
// at each bucket tail (xoff=0, norm=0) - always initialized memory.
__device__ inline void b4rec(const uint2* __restrict__ csr, int base, uint2 q[4]) {
#pragma unroll
  for (int j = 0; j < 4; ++j) q[j] = csr[base + j];
}
__device__ inline void b4xr(const uint2 q[4],
                            const char* __restrict__ Xb, const char* __restrict__ Rb,
                            unsigned lxc, unsigned lr, f16x2 xv[4], f16x4 rv[4]) {
#pragma unroll
  for (int j = 0; j < 4; ++j) {
    xv[j] = *(const f16x2*)(Xb + q[j].x + lxc);
    rv[j] = *(const f16x4*)(Rb + ((q[j].y & 0x1FFu) << 9) + lr);
  }
}
__device__ inline void b4math(const uint2 q[4], int base, int end,
                              const f16x2 xv[4], const f16x4 rv[4],
                              float& ax, float& ay) {
#pragma unroll
  for (int j = 0; j < 4; ++j) {
    unsigned nb = (base + j < end) ? (q[j].y >> 16) : 0u;
    HU32 nm; nm.u = nb | (nb << 16);
    f16x2 xs = xv[j] * nm.h;
    ax = dot2f(xs, (f16x2){rv[j][0], rv[j][1]}, ax);
    ay = dot2f(xs, (f16x2){rv[j][2], rv[j][3]}, ay);
  }
}

__global__ __launch_bounds__(256) void k_agg(
    _Float16* __restrict__ Abuf, const _Float16* __restrict__ RfL,
    const uint2* __restrict__ csrIn, const int2* __restrict__ beI,
    const uint2* __restrict__ csrOut, const int2* __restrict__ beO) {
  const int w = threadIdx.x >> 6, l = threadIdx.x & 63;
  const int v = blockIdx.x * 4 + w;
  const char* Xb = (const char*)Abuf;
  const char* Rb = (const char*)RfL;
  const unsigned lxc = 512u + (unsigned)l * 4u;
  const unsigned lr = (unsigned)l * 8u;
  int2 bi = beI[v], bo = beO[v];
  int i  = __builtin_amdgcn_readfirstlane(bi.x);
  int ie = __builtin_amdgcn_readfirstlane(bi.y);
  int o  = __builtin_amdgcn_readfirstlane(bo.x);
  int oe = __builtin_amdgcn_readfirstlane(bo.y);
  int nbi = (ie - i + 3) >> 2;
  int nbo = (oe - o + 3) >> 2;
  float aix = 0.f, aiy = 0.f, aox = 0.f, aoy = 0.f;

  uint2 qa[4], qb[4];
  if (nbi > 0) b4rec(csrIn, i, qa);
  if (nbo > 0) b4rec(csrOut, o, qb);

  while (nbi > 0 && nbo > 0) {
    f16x2 xa[4], xb[4]; f16x4 ra[4], rb[4];
    b4xr(qa, Xb, Rb, lxc, lr, xa, ra);
    b4xr(qb, Xb, Rb, lxc, lr, xb, rb);
    uint2 qa2[4], qb2[4];
    b4rec(csrIn, i + 4, qa2);
    b4rec(csrOut, o + 4, qb2);
    b4math(qa, i, ie, xa, ra, aix, aiy);
    b4math(qb, o, oe, xb, rb, aox, aoy);
#pragma unroll
    for (int j = 0; j < 4; ++j) { qa[j] = qa2[j]; qb[j] = qb2[j]; }
    i += 4; o += 4; --nbi; --nbo;
  }
  while (nbi > 0) {
    f16x2 xa[4]; f16x4 ra[4];
    b4xr(qa, Xb, Rb, lxc, lr, xa, ra);
    uint2 qa2[4];
    b4rec(csrIn, i + 4, qa2);
    b4math(qa, i, ie, xa, ra, aix, aiy);
#pragma unroll
    for (int j = 0; j < 4; ++j) qa[j] = qa2[j];
    i += 4; --nbi;
  }
  while (nbo > 0) {
    f16x2 xb[4]; f16x4 rb[4];
    b4xr(qb, Xb, Rb, lxc, lr, xb, rb);
    uint2 qb2[4];
    b4rec(csrOut, o + 4, qb2);
    b4math(qb, o, oe, xb, rb, aox, aoy);
#pragma unroll
    for (int j = 0; j < 4; ++j) qb[j] = qb2[j];
    o += 4; --nbo;
  }

  *(f16x2*)((char*)Abuf + (size_t)v * 768 + 4u * l) = (f16x2){(_Float16)aix, (_Float16)aiy};
  *(f16x2*)((char*)Abuf + (size_t)v * 768 + 256 + 4u * l) = (f16x2){(_Float16)aox, (_Float16)aoy};
}

extern "C" void kernel_launch(void* const* d_in, const int* in_sizes, int n_in,
                              void* d_out, int out_size, void* d_ws, size_t ws_size,
                              hipStream_t stream) {
  const float* x       = (const float*)d_in[0];
  const float* rel     = (const float*)d_in[1];
  const float* w_in    = (const float*)d_in[2];
  const float* w_out   = (const float*)d_in[3];
  const float* w_loop  = (const float*)d_in[4];
  const float* w_rel   = (const float*)d_in[5];
  const float* looprel = (const float*)d_in[6];
  const float* bias    = (const float*)d_in[7];
  const float* bnw     = (const float*)d_in[8];
  const float* bnb     = (const float*)d_in[9];
  const int*   ei      = (const int*)d_in[10];
  const int*   et      = (const int*)d_in[11];
  float* out = (float*)d_out;

  char* p = (char*)d_ws;
  auto alloc = [&](size_t bytes) -> void* {
    void* r = (void*)p;
    p += (bytes + 255) & ~(size_t)255;
    return r;
  };
  _Float16* Abuf  = (_Float16*)alloc((size_t)N_ENT * 384 * 2);
  _Float16* tmpC  = (_Float16*)alloc((size_t)N_ENT * 128 * 2);
  _Float16* WT    = (_Float16*)alloc(128 * 384 * 2);
  _Float16* WrT   = (_Float16*)alloc(128 * 128 * 2);
  _Float16* FtabT = (_Float16*)alloc(128 * 128 * 2);
  _Float16* RfL   = (_Float16*)alloc(501 * 64 * 4 * 2);
  float* Wstack   = (float*)alloc(384 * 128 * 4);
  float* Ftab     = (float*)alloc(128 * 128 * 4);
  float* Gtab     = (float*)alloc(128 * 128 * 4);
  float* Rf       = (float*)alloc(501 * 128 * 4);
  float* dinvIn   = (float*)alloc(N_ENT * 4);
  float* dinvOut  = (float*)alloc(N_ENT * 4);
  int*   gcur     = (int*)alloc(4 * NBUK * 4);   // gSI|gSO|gDI|gDO (relative)
  int2*  beI      = (int2*)alloc((size_t)N_ENT * 8);
  int2*  beO      = (int2*)alloc((size_t)N_ENT * 8);
  unsigned* recSI = (unsigned*)alloc((size_t)NBUK * SCAP * 4);
  unsigned* recSO = (unsigned*)alloc((size_t)NBUK * SCAP * 4);
  uint2* recDI    = (uint2*)alloc((size_t)NBUK * DCAP * 8);
  uint2* recDO    = (uint2*)alloc((size_t)NBUK * DCAP * 8);
  uint2* csrIn    = (uint2*)alloc((size_t)NBUK * DCAP * 8);
  uint2* csrOut   = (uint2*)alloc((size_t)NBUK * DCAP * 8);
  float* bnAcc    = (float*)alloc(256 * 4);

  int* gSI = gcur;
  int* gSO = gcur + NBUK;
  int* gDI = gcur + 2 * NBUK;
  int* gDO = gcur + 3 * NBUK;

  // L1: tables + cursor/bnAcc zeroing
  k_tabs<<<64, 256, 0, stream>>>(Ftab, Gtab, FtabT, gcur, bnAcc);

  // L2: split (4 phases) || rel-DFT
  k_sd<<<4 * NSB + 251, 256, 0, stream>>>(ei, et, gcur, recSI, recSO, recDI, recDO,
                                          rel, looprel, Ftab, Rf, RfL);

  // L3: Xf = rfft(x) via f16 MFMA into Abuf cols [256..384)
  k_xf<<<XFB, 256, 0, stream>>>(x, FtabT, Abuf);

  // L4: Wstack prep GEMMs
  k_wprep<<<6, 256, 0, stream>>>(Gtab, w_in, w_out, w_loop, Wstack);

  // L5: degrees -> dinv
  k_dhist<<<2 * NBUK, 512, 0, stream>>>(recSI, gSI, dinvIn, recSO, gSO, dinvOut);

  // L6: fine sort -> CSR || WT transpose (+rotation) || w_rel transpose
  k_fw<<<2 * NBUK + 96 + 32, 512, 0, stream>>>(
      recDI, gDI, csrIn, beI, recDO, gDO, csrOut, beO, dinvIn, dinvOut,
      Wstack, Rf + 500 * 128, WT, w_rel, WrT);

  // L7: frequency-domain aggregation (rec-prefetch software pipeline)
  k_agg<<<N_ENT / 4, 256, 0, stream>>>(Abuf, RfL, csrIn, beI, csrOut, beO);

  // L8: output GEMM + bias -> f16 tmp + BN stats || rel_out GEMM (fp32 C)
  k_out<<<XFB + 2, 256, 0, stream>>>(Abuf, WT, tmpC, bias, bnAcc, rel, WrT, out);

  // L9: BN normalize -> fp32 out
  k_norm<<<(N_ENT * 128 / 8) / 256, 256, 0, stream>>>(tmpC, out, bnAcc, bnw, bnb);
}